// Round 5
// baseline (194.915 us; speedup 1.0000x reference)
//
#include <hip/hip_runtime.h>

#define NN 10000    // nodes
#define RR 100      // relations
#define EE 5000     // edges per relation
#define D0 2048
#define D1 128
#define D2 64
#define D3 20
#define NE (RR*EE)  // 500000 edges total
#define MAXD 128    // fixed CSR stride per node (true max deg ~80, 11 sigma)

using short8  = __attribute__((ext_vector_type(8))) short;
using float4e = __attribute__((ext_vector_type(4))) float;

__device__ __forceinline__ unsigned short f2bf(float f) {
  unsigned int u = __float_as_uint(f);
  unsigned int r = u + 0x7fffu + ((u >> 16) & 1u);   // RNE
  return (unsigned short)(r >> 16);
}
__device__ __forceinline__ float bf2f(unsigned short u) {
  return __uint_as_float(((unsigned int)u) << 16);
}
__device__ __forceinline__ unsigned int pk2(float lo, float hi) {
  return ((unsigned int)f2bf(hi) << 16) | (unsigned int)f2bf(lo);
}

// ---------------------------------------------------------------------------
// prep: fused {zero deg, zero cur, wtrans, wc1t, wc2t} in one dispatch
// ---------------------------------------------------------------------------
#define ZBLK 977            // 250,000 int4 zeros (deg)
#define CURB 10             // 2,504 int4 zeros (cur)
#define WTBLK 1024          // 262,144 elems
#define W1BLK 288           // 73,728 elems
#define W2BLK 72            // 18,432 elems
__global__ __launch_bounds__(256) void prep_kernel(
    const float* __restrict__ W, const float* __restrict__ root1,
    const float* __restrict__ basis1, const float* __restrict__ root2,
    const float* __restrict__ basis2, int4* __restrict__ deg4,
    int4* __restrict__ cur4,
    unsigned short* __restrict__ Btw, unsigned short* __restrict__ Wc1T,
    unsigned short* __restrict__ Wc2T) {
  const int b = blockIdx.x, tid = threadIdx.x;
  if (b < ZBLK) {
    int i = b * 256 + tid;
    if (i < (NN * RR) / 4) deg4[i] = make_int4(0, 0, 0, 0);
  } else if (b < ZBLK + CURB) {
    int i = (b - ZBLK) * 256 + tid;
    if (i < 2504) cur4[i] = make_int4(0, 0, 0, 0);
  } else if (b < ZBLK + CURB + WTBLK) {
    int idx = (b - ZBLK - CURB) * 256 + tid;                 // 128*2048, exact
    int n = idx >> 11, k = idx & 2047;
    Btw[idx] = f2bf(W[(size_t)k * 128 + n]);
  } else if (b < ZBLK + CURB + WTBLK + W1BLK) {
    int idx = (b - ZBLK - CURB - WTBLK) * 256 + tid;         // 64*1152, exact
    int o = idx / 1152, j = idx - o * 1152;
    float v = (j < 128) ? root1[j * 64 + o] : basis1[(j - 128) * 64 + o];
    Wc1T[idx] = f2bf(v);
  } else {
    int idx = (b - ZBLK - CURB - WTBLK - W1BLK) * 256 + tid; // 32*576, exact
    int c = idx / 576, j = idx - c * 576;
    float v = 0.f;
    if (c < 20) v = (j < 64) ? root2[j * 20 + c] : basis2[(j - 64) * 20 + c];
    Wc2T[idx] = f2bf(v);
  }
}

// ---------------------------------------------------------------------------
// CSR build — fixed-stride (MAXD per node): no cnt/scan kernels needed.
// ---------------------------------------------------------------------------
__global__ void deg_kernel(const int* __restrict__ ei, int* __restrict__ deg) {
  int gid = blockIdx.x * 256 + threadIdx.x;
  if (gid >= NE) return;
  int r = gid / EE, e = gid - r * EE;
  int d = ei[r * 2 * EE + EE + e];
  atomicAdd(&deg[r * NN + d], 1);
}

// rec = (r<<14)|src, esc = 1/max(deg,1); slot = atomic bump of cur[d]
__global__ void scatter_kernel(const int* __restrict__ ei,
                               const int* __restrict__ deg,
                               int* __restrict__ cur, int* __restrict__ rec,
                               float* __restrict__ esc) {
  int gid = blockIdx.x * 256 + threadIdx.x;
  if (gid >= NE) return;
  int r = gid / EE, e = gid - r * EE;
  int s = ei[r * 2 * EE + e];
  int d = ei[r * 2 * EE + EE + e];
  int p = atomicAdd(&cur[d], 1);
  if (p < MAXD) {
    rec[d * MAXD + p] = (r << 14) | s;
    esc[d * MAXD + p] = 1.0f / fmaxf((float)deg[r * NN + d], 1.0f);
  }
}

// ---------------------------------------------------------------------------
// gemm0: xp[ks] = x_drug[:, ks*512:+512] @ drug_w[ks*512:,:]  (K-split 4)
// bf16 MFMA 16x16x32; tile M=64, N=128, BK=64; grid (157,4)=628 blocks at
// 48KB LDS -> 3 blocks/CU = 768 slots >= 628: ALL blocks resident from t=0
// (kills the 22% occupancy tail of the (313,4)@4/CU shape). 16 MFMA per wave
// per barrier. Double-buffered XOR-swizzled LDS + 2-deep register prefetch.
// ---------------------------------------------------------------------------
__global__ __launch_bounds__(256, 3) void gemm0_mfma(
    const float* __restrict__ A, const unsigned short* __restrict__ Btw,
    float* __restrict__ xp) {
  __shared__ __align__(16) unsigned short Asb[2][64 * 64];    // 2 x 8 KB
  __shared__ __align__(16) unsigned short Bsb[2][128 * 64];   // 2 x 16 KB
  const int tid = threadIdx.x;
  const int m0 = blockIdx.x * 64;
  const int ks = blockIdx.y;
  const int wv = tid >> 6, lane = tid & 63;
  const int lrow = lane & 15, quad = lane >> 4;
  const int mt = wv;                // each wave owns a 16-row slice

  // A staging: 64 rows x 64 K fp32->bf16. ar=tid>>2 (64 rows), aq=tid&3
  // loads 16 consecutive floats (4x float4, 64B/thread, coalesced 256B/row).
  const int ar = tid >> 2, aq = tid & 3;
  int gra = m0 + ar; if (gra >= NN) gra = NN - 1;
  const float* Ap = &A[(size_t)gra * D0 + ks * 512 + aq * 16];
  const int asw = (ar & 7) << 4;
  const int aw0 = (ar * 128 + ((aq * 32) ^ asw)) >> 1;        // ushort idx
  const int aw1 = (ar * 128 + ((aq * 32 + 16) ^ asw)) >> 1;

  // B staging: 128 rows x 64 K bf16. br=tid>>1 (128 rows), bh=tid&1 (32 elems).
  const int br = tid >> 1, bh = tid & 1;
  const unsigned short* Bp = &Btw[(size_t)br * D0 + ks * 512 + bh * 32];
  const int bsw = (br & 7) << 4;
  int bw[4];
#pragma unroll
  for (int j = 0; j < 4; j++)
    bw[j] = (br * 128 + ((bh * 64 + j * 16) ^ bsw)) >> 1;

  // two in-flight register sets (X = even steps, Y = odd steps)
  float4 Xa[4], Ya[4];
  uint4 Xb[4], Yb[4];

#define G0_LOADG(P, c)                                        \
  { _Pragma("unroll")                                         \
    for (int j = 0; j < 4; j++) {                             \
      P##a[j] = *(const float4*)(Ap + (c) * 64 + j * 4);      \
      P##b[j] = *(const uint4*)(Bp + (c) * 64 + j * 8);       \
    } }

#define G0_STOREL(buf, P)                                               \
  { uint4 q0, q1;                                                       \
    q0.x = pk2(P##a[0].x, P##a[0].y); q0.y = pk2(P##a[0].z, P##a[0].w); \
    q0.z = pk2(P##a[1].x, P##a[1].y); q0.w = pk2(P##a[1].z, P##a[1].w); \
    q1.x = pk2(P##a[2].x, P##a[2].y); q1.y = pk2(P##a[2].z, P##a[2].w); \
    q1.z = pk2(P##a[3].x, P##a[3].y); q1.w = pk2(P##a[3].z, P##a[3].w); \
    *(uint4*)&Asb[buf][aw0] = q0;                                       \
    *(uint4*)&Asb[buf][aw1] = q1;                                       \
    _Pragma("unroll")                                                   \
    for (int j = 0; j < 4; j++) *(uint4*)&Bsb[buf][bw[j]] = P##b[j]; }

#define G0_COMPUTE(buf)                                                 \
  { const int arow = mt * 16 + lrow;                                    \
    const int aswz = (arow & 7) << 4;                                   \
    _Pragma("unroll")                                                   \
    for (int kk = 0; kk < 2; kk++) {                                    \
      short8 af = *(const short8*)&Asb[buf][(arow * 128 + ((quad * 16 + kk * 64) ^ aswz)) >> 1]; \
      _Pragma("unroll")                                                 \
      for (int nt = 0; nt < 8; nt++) {                                  \
        const int brow = nt * 16 + lrow;                                \
        short8 bfr = *(const short8*)&Bsb[buf][(brow * 128 + ((quad * 16 + kk * 64) ^ ((brow & 7) << 4))) >> 1]; \
        acc[nt] = __builtin_amdgcn_mfma_f32_16x16x32_bf16(af, bfr, acc[nt], 0, 0, 0); \
      }                                                                 \
    } }

  float4e acc[8];
#pragma unroll
  for (int i = 0; i < 8; i++) { acc[i][0]=0.f; acc[i][1]=0.f; acc[i][2]=0.f; acc[i][3]=0.f; }

  // prologue: steps 0 and 1 in flight; stage step 0
  G0_LOADG(X, 0);
  G0_LOADG(Y, 1);
  G0_STOREL(0, X);
  __syncthreads();

  // iter c: load step c+2 (into the set freed last iter), compute step c,
  // store step c+1 into the other LDS buffer. One barrier per step.
#pragma unroll
  for (int c = 0; c < 8; c++) {
    if (c < 6) {
      if ((c & 1) == 0) { G0_LOADG(X, c + 2); } else { G0_LOADG(Y, c + 2); }
    }
    G0_COMPUTE(c & 1);
    if (c < 7) {
      if ((c & 1) == 0) { G0_STOREL(1, Y); } else { G0_STOREL(0, X); }
    }
    __syncthreads();
  }

#pragma unroll
  for (int nt = 0; nt < 8; nt++) {
    const int col = nt * 16 + lrow;
#pragma unroll
    for (int r = 0; r < 4; r++) {
      const int row = m0 + mt * 16 + quad * 4 + r;
      if (row < NN)
        xp[(size_t)ks * (NN * D1) + (size_t)row * D1 + col] = acc[nt][r];
    }
  }
}

// xb = bf16(xp0+xp1+xp2+xp3)
__global__ void reduce_kernel(const float* __restrict__ xp,
                              unsigned short* __restrict__ xb) {
  int idx = (blockIdx.x * 256 + threadIdx.x) * 4;
  if (idx >= NN * D1) return;
  float4 a = *(const float4*)&xp[idx];
  float4 b = *(const float4*)&xp[NN * D1 + idx];
  float4 c = *(const float4*)&xp[2 * NN * D1 + idx];
  float4 d = *(const float4*)&xp[3 * NN * D1 + idx];
  ushort4 o;
  o.x = f2bf(a.x + b.x + c.x + d.x); o.y = f2bf(a.y + b.y + c.y + d.y);
  o.z = f2bf(a.z + b.z + c.z + d.z); o.w = f2bf(a.w + b.w + c.w + d.w);
  *(ushort4*)&xb[idx] = o;
}

// ---------------------------------------------------------------------------
// agg1e: A1b[n, b*128+i] = bf16( sum_{e->n} esc_e*comp1[r_e,b]*x[src_e,i] )
// one wave per node; lane holds 2 of 128 channels; 4-edge unroll
// ---------------------------------------------------------------------------
__global__ __launch_bounds__(256) void agg1e_kernel(
    const unsigned short* __restrict__ xb, const int* __restrict__ cur,
    const int* __restrict__ rec, const float* __restrict__ esc,
    const float* __restrict__ comp, unsigned short* __restrict__ A1b) {
  __shared__ float s_comp[RR * 8];
  const int tid = threadIdx.x;
  for (int i = tid; i < RR * 8; i += 256) s_comp[i] = comp[i];
  __syncthreads();
  const int wv = tid >> 6, lane = tid & 63;
  const int n = blockIdx.x * 4 + wv;
  if (n >= NN) return;
  float acc[8][2];
#pragma unroll
  for (int b = 0; b < 8; b++) { acc[b][0] = 0.f; acc[b][1] = 0.f; }
  int cnt = cur[n]; if (cnt > MAXD) cnt = MAXD;
  const int beg = n * MAXD, end = beg + cnt;
  int idx = beg;
  for (; idx + 3 < end; idx += 4) {
    int rc[4]; float sc[4]; unsigned int xv[4];
#pragma unroll
    for (int u = 0; u < 4; u++) {
      rc[u] = rec[idx + u];
      sc[u] = esc[idx + u];
    }
#pragma unroll
    for (int u = 0; u < 4; u++)
      xv[u] = *(const unsigned int*)&xb[(size_t)(rc[u] & 16383) * D1 + lane * 2];
#pragma unroll
    for (int u = 0; u < 4; u++) {
      const float* cb = &s_comp[(rc[u] >> 14) * 8];
      float x0 = __uint_as_float((xv[u] & 0xffffu) << 16);
      float x1 = __uint_as_float(xv[u] & 0xffff0000u);
#pragma unroll
      for (int b = 0; b < 8; b++) {
        float w = sc[u] * cb[b];
        acc[b][0] += w * x0;
        acc[b][1] += w * x1;
      }
    }
  }
  for (; idx < end; idx++) {
    int rc = rec[idx];
    float sc = esc[idx];
    unsigned int xv = *(const unsigned int*)&xb[(size_t)(rc & 16383) * D1 + lane * 2];
    const float* cb = &s_comp[(rc >> 14) * 8];
    float x0 = __uint_as_float((xv & 0xffffu) << 16);
    float x1 = __uint_as_float(xv & 0xffff0000u);
#pragma unroll
    for (int b = 0; b < 8; b++) {
      float w = sc * cb[b];
      acc[b][0] += w * x0;
      acc[b][1] += w * x1;
    }
  }
#pragma unroll
  for (int b = 0; b < 8; b++) {
    ushort2 o; o.x = f2bf(acc[b][0]); o.y = f2bf(acc[b][1]);
    *(ushort2*)&A1b[(size_t)n * 1024 + b * 128 + lane * 2] = o;
  }
}

// ---------------------------------------------------------------------------
// agg2e: A2b[n, b*64+i] = bf16( sum_{e->n} esc_e*comp2[r_e,b]*h[src_e,i] )
// ---------------------------------------------------------------------------
__global__ __launch_bounds__(256) void agg2e_kernel(
    const unsigned short* __restrict__ hb, const int* __restrict__ cur,
    const int* __restrict__ rec, const float* __restrict__ esc,
    const float* __restrict__ comp, unsigned short* __restrict__ A2b) {
  __shared__ float s_comp[RR * 8];
  const int tid = threadIdx.x;
  for (int i = tid; i < RR * 8; i += 256) s_comp[i] = comp[i];
  __syncthreads();
  const int wv = tid >> 6, lane = tid & 63;
  const int n = blockIdx.x * 4 + wv;
  if (n >= NN) return;
  float acc[8];
#pragma unroll
  for (int b = 0; b < 8; b++) acc[b] = 0.f;
  int cnt = cur[n]; if (cnt > MAXD) cnt = MAXD;
  const int beg = n * MAXD, end = beg + cnt;
  int idx = beg;
  for (; idx + 3 < end; idx += 4) {
    int rc[4]; float sc[4]; float hv[4];
#pragma unroll
    for (int u = 0; u < 4; u++) {
      rc[u] = rec[idx + u];
      sc[u] = esc[idx + u];
    }
#pragma unroll
    for (int u = 0; u < 4; u++)
      hv[u] = bf2f(hb[(size_t)(rc[u] & 16383) * D2 + lane]);
#pragma unroll
    for (int u = 0; u < 4; u++) {
      const float* cb = &s_comp[(rc[u] >> 14) * 8];
#pragma unroll
      for (int b = 0; b < 8; b++) acc[b] += sc[u] * cb[b] * hv[u];
    }
  }
  for (; idx < end; idx++) {
    int rc = rec[idx];
    float sc = esc[idx];
    float hv = bf2f(hb[(size_t)(rc & 16383) * D2 + lane]);
    const float* cb = &s_comp[(rc >> 14) * 8];
#pragma unroll
    for (int b = 0; b < 8; b++) acc[b] += sc * cb[b] * hv;
  }
#pragma unroll
  for (int b = 0; b < 8; b++)
    A2b[(size_t)n * 512 + b * 64 + lane] = f2bf(acc[b]);
}

// ---------------------------------------------------------------------------
// hlayer: hb = bf16(relu([xb|A1b](K=1152) @ Wc1T + bias1))
// MFMA, tile M=32 x N=64 (313 blocks), register-prefetch pipeline
// ---------------------------------------------------------------------------
__global__ __launch_bounds__(256) void hlayer_mfma(
    const unsigned short* __restrict__ xb, const unsigned short* __restrict__ A1b,
    const unsigned short* __restrict__ Wt, const float* __restrict__ bias1,
    unsigned short* __restrict__ hb) {
  __shared__ unsigned short Asb[32][40];
  __shared__ unsigned short Bsb[64][40];
  const int tid = threadIdx.x;
  const int m0 = blockIdx.x * 32;
  const int wv = tid >> 6, lane = tid & 63;
  const int lrow = lane & 15, quad = lane >> 4;
  const int mt = wv >> 1, ntb = (wv & 1) * 2;

  const int brow = tid >> 2, bq = tid & 3;          // B: 64 rows
  const int as_row = (tid & 127) >> 2;              // A: 32 rows (tid<128)
  int gr = m0 + as_row; if (gr >= NN) gr = NN - 1;
  const unsigned short* Arow_x = &xb[(size_t)gr * D1 + bq * 8];
  const unsigned short* Arow_a = &A1b[(size_t)gr * 1024 + bq * 8];
  const unsigned short* Bp = &Wt[(size_t)brow * 1152 + bq * 8];

  uint4 ra0, ra1, rb0, rb1;

#define H_LOAD(ra, rb, c)                                                    \
  { int kb = (c) * 32;                                                       \
    if (tid < 128)                                                           \
      ra = (kb < 128) ? *(const uint4*)(Arow_x + kb)                         \
                      : *(const uint4*)(Arow_a + (kb - 128));                \
    rb = *(const uint4*)(Bp + kb); }

#define H_STORE(ra, rb)                                                      \
  { if (tid < 128) *(uint4*)&Asb[as_row][bq * 8] = ra;                       \
    *(uint4*)&Bsb[brow][bq * 8] = rb; }

#define H_COMPUTE()                                                          \
  { short8 af = *(const short8*)&Asb[mt * 16 + lrow][quad * 8];              \
    _Pragma("unroll")                                                        \
    for (int ntl = 0; ntl < 2; ntl++) {                                      \
      short8 bfr = *(const short8*)&Bsb[(ntb + ntl) * 16 + lrow][quad * 8];  \
      acc[ntl] = __builtin_amdgcn_mfma_f32_16x16x32_bf16(af, bfr, acc[ntl], 0, 0, 0); \
    } }

  float4e acc[2];
#pragma unroll
  for (int i = 0; i < 2; i++) { acc[i][0]=0.f; acc[i][1]=0.f; acc[i][2]=0.f; acc[i][3]=0.f; }

  H_LOAD(ra0, rb0, 0);
  for (int c = 0; c < 36; c += 2) {
    H_STORE(ra0, rb0);
    __syncthreads();
    if (c + 1 < 36) H_LOAD(ra1, rb1, c + 1);
    H_COMPUTE();
    __syncthreads();
    H_STORE(ra1, rb1);
    __syncthreads();
    if (c + 2 < 36) H_LOAD(ra0, rb0, c + 2);
    H_COMPUTE();
    __syncthreads();
  }

#pragma unroll
  for (int ntl = 0; ntl < 2; ntl++) {
    int col = (ntb + ntl) * 16 + lrow;
    float bv = bias1[col];
#pragma unroll
    for (int r = 0; r < 4; r++) {
      int row = m0 + mt * 16 + quad * 4 + r;
      if (row < NN)
        hb[(size_t)row * D2 + col] = f2bf(fmaxf(acc[ntl][r] + bv, 0.f));
    }
  }
}

// ---------------------------------------------------------------------------
// out: out = [hb|A2b](K=576) @ Wc2T + bias2
// MFMA, tile M=32 x N=32 (313 blocks), register-prefetch pipeline
// ---------------------------------------------------------------------------
__global__ __launch_bounds__(256) void out_mfma(
    const unsigned short* __restrict__ hb, const unsigned short* __restrict__ A2b,
    const unsigned short* __restrict__ Wt, const float* __restrict__ bias2,
    float* __restrict__ out) {
  __shared__ unsigned short Asb[32][40];
  __shared__ unsigned short Bsb[32][40];
  const int tid = threadIdx.x;
  const int m0 = blockIdx.x * 32;
  const int wv = tid >> 6, lane = tid & 63;
  const int lrow = lane & 15, quad = lane >> 4;
  const int mt = wv >> 1, nt = wv & 1;

  const int srow = (tid & 127) >> 2, sq = tid & 3;  // 32 rows per half
  int gr = m0 + srow; if (gr >= NN) gr = NN - 1;
  const unsigned short* Arow_h = &hb[(size_t)gr * D2 + sq * 8];
  const unsigned short* Arow_a = &A2b[(size_t)gr * 512 + sq * 8];
  const unsigned short* Bp = &Wt[(size_t)srow * 576 + sq * 8];

  uint4 r0, r1;

#define O_LOAD(rg, c)                                                        \
  { int kb = (c) * 32;                                                       \
    if (tid < 128)                                                           \
      rg = (kb < 64) ? *(const uint4*)(Arow_h + kb)                          \
                     : *(const uint4*)(Arow_a + (kb - 64));                  \
    else                                                                     \
      rg = *(const uint4*)(Bp + kb); }

#define O_STORE(rg)                                                          \
  { if (tid < 128) *(uint4*)&Asb[srow][sq * 8] = rg;                         \
    else           *(uint4*)&Bsb[srow][sq * 8] = rg; }

#define O_COMPUTE()                                                          \
  { short8 af = *(const short8*)&Asb[mt * 16 + lrow][quad * 8];              \
    short8 bfr = *(const short8*)&Bsb[nt * 16 + lrow][quad * 8];             \
    acc = __builtin_amdgcn_mfma_f32_16x16x32_bf16(af, bfr, acc, 0, 0, 0); }

  float4e acc;
  acc[0]=0.f; acc[1]=0.f; acc[2]=0.f; acc[3]=0.f;

  O_LOAD(r0, 0);
  for (int c = 0; c < 18; c += 2) {
    O_STORE(r0);
    __syncthreads();
    if (c + 1 < 18) O_LOAD(r1, c + 1);
    O_COMPUTE();
    __syncthreads();
    O_STORE(r1);
    __syncthreads();
    if (c + 2 < 18) O_LOAD(r0, c + 2);
    O_COMPUTE();
    __syncthreads();
  }

  int col = nt * 16 + lrow;
  if (col < D3) {
    float bv = bias2[col];
#pragma unroll
    for (int r = 0; r < 4; r++) {
      int row = m0 + mt * 16 + quad * 4 + r;
      if (row < NN)
        out[(size_t)row * D3 + col] = acc[r] + bv;
    }
  }
}

// ---------------------------------------------------------------------------
extern "C" void kernel_launch(void* const* d_in, const int* in_sizes, int n_in,
                              void* d_out, int out_size, void* d_ws,
                              size_t ws_size, hipStream_t stream) {
  const float* x_drug = (const float*)d_in[0];
  const float* drug_w = (const float*)d_in[1];
  const int*   ei     = (const int*)d_in[2];
  const float* basis1 = (const float*)d_in[3];
  const float* comp1  = (const float*)d_in[4];
  const float* root1  = (const float*)d_in[5];
  const float* bias1  = (const float*)d_in[6];
  const float* basis2 = (const float*)d_in[7];
  const float* comp2  = (const float*)d_in[8];
  const float* root2  = (const float*)d_in[9];
  const float* bias2  = (const float*)d_in[10];
  float* out = (float*)d_out;

  float* ws = (float*)d_ws;
  int*   deg  = (int*)ws;                          // 1,000,000
  int*   cur  = deg + 1000000;                     // 10,016
  int*   rec  = cur + 10016;                       // 1,280,000 (NN*MAXD)
  float* esc  = (float*)(rec + NN * MAXD);         // 1,280,000
  unsigned short* xb   = (unsigned short*)(esc + NN * MAXD);       // 640,000 f
  unsigned short* hb   = (unsigned short*)((float*)xb + 640000);   // 320,000 f
  unsigned short* Btw  = (unsigned short*)((float*)hb + 320000);   // 131,072 f
  unsigned short* Wc1T = (unsigned short*)((float*)Btw + 131072);  // 36,864 f
  unsigned short* Wc2T = (unsigned short*)((float*)Wc1T + 36864);  // 9,216 f
  float* R1 = (float*)Wc2T + 9216;                 // 5,120,000 floats shared
  float* xp = R1;                                  // 4 x 1,280,000 fp32 partials
  unsigned short* A1b = (unsigned short*)R1;       // aliases xp (after reduce)
  unsigned short* A2b = (unsigned short*)R1;       // aliases A1b (after hlayer)

  // fused prep: zero deg/cur + all weight transposes (one dispatch)
  prep_kernel<<<ZBLK + CURB + WTBLK + W1BLK + W2BLK, 256, 0, stream>>>(
      drug_w, root1, basis1, root2, basis2, (int4*)deg, (int4*)cur,
      Btw, Wc1T, Wc2T);

  // CSR build: fixed-stride slots, no cnt/scan
  deg_kernel<<<(NE + 255) / 256, 256, 0, stream>>>(ei, deg);
  scatter_kernel<<<(NE + 255) / 256, 256, 0, stream>>>(ei, deg, cur, rec, esc);

  // x = x_drug @ drug_w (bf16 MFMA, K-split 4 + reduce)
  gemm0_mfma<<<dim3(157, 4), 256, 0, stream>>>(x_drug, Btw, xp);
  reduce_kernel<<<(NN * D1 / 4 + 255) / 256, 256, 0, stream>>>(xp, xb);

  // layer 1
  agg1e_kernel<<<(NN + 3) / 4, 256, 0, stream>>>(xb, cur, rec, esc, comp1, A1b);
  hlayer_mfma<<<(NN + 31) / 32, 256, 0, stream>>>(xb, A1b, Wc1T, bias1, hb);

  // layer 2
  agg2e_kernel<<<(NN + 3) / 4, 256, 0, stream>>>(hb, cur, rec, esc, comp2, A2b);
  out_mfma<<<(NN + 31) / 32, 256, 0, stream>>>(hb, A2b, Wc2T, bias2, out);
}

// Round 6
// 177.915 us; speedup vs baseline: 1.0955x; 1.0955x over previous
//
#include <hip/hip_runtime.h>

#define NN 10000    // nodes
#define RR 100      // relations
#define EE 5000     // edges per relation
#define D0 2048
#define D1 128
#define D2 64
#define D3 20
#define NE (RR*EE)  // 500000 edges total
#define MAXD 128    // fixed CSR stride per node (true max deg ~80, 11 sigma)

using short8  = __attribute__((ext_vector_type(8))) short;
using float4e = __attribute__((ext_vector_type(4))) float;

__device__ __forceinline__ unsigned short f2bf(float f) {
  unsigned int u = __float_as_uint(f);
  unsigned int r = u + 0x7fffu + ((u >> 16) & 1u);   // RNE
  return (unsigned short)(r >> 16);
}
__device__ __forceinline__ float bf2f(unsigned short u) {
  return __uint_as_float(((unsigned int)u) << 16);
}
__device__ __forceinline__ unsigned int pk2(float lo, float hi) {
  return ((unsigned int)f2bf(hi) << 16) | (unsigned int)f2bf(lo);
}

// ---------------------------------------------------------------------------
// prep: fused {zero deg, zero cur, wtrans, wc1t, wc2t} in one dispatch
// ---------------------------------------------------------------------------
#define ZBLK 977            // 250,000 int4 zeros (deg)
#define CURB 10             // 2,504 int4 zeros (cur)
#define WTBLK 1024          // 262,144 elems
#define W1BLK 288           // 73,728 elems
#define W2BLK 72            // 18,432 elems
__global__ __launch_bounds__(256) void prep_kernel(
    const float* __restrict__ W, const float* __restrict__ root1,
    const float* __restrict__ basis1, const float* __restrict__ root2,
    const float* __restrict__ basis2, int4* __restrict__ deg4,
    int4* __restrict__ cur4,
    unsigned short* __restrict__ Btw, unsigned short* __restrict__ Wc1T,
    unsigned short* __restrict__ Wc2T) {
  const int b = blockIdx.x, tid = threadIdx.x;
  if (b < ZBLK) {
    int i = b * 256 + tid;
    if (i < (NN * RR) / 4) deg4[i] = make_int4(0, 0, 0, 0);
  } else if (b < ZBLK + CURB) {
    int i = (b - ZBLK) * 256 + tid;
    if (i < 2504) cur4[i] = make_int4(0, 0, 0, 0);
  } else if (b < ZBLK + CURB + WTBLK) {
    int idx = (b - ZBLK - CURB) * 256 + tid;                 // 128*2048, exact
    int n = idx >> 11, k = idx & 2047;
    Btw[idx] = f2bf(W[(size_t)k * 128 + n]);
  } else if (b < ZBLK + CURB + WTBLK + W1BLK) {
    int idx = (b - ZBLK - CURB - WTBLK) * 256 + tid;         // 64*1152, exact
    int o = idx / 1152, j = idx - o * 1152;
    float v = (j < 128) ? root1[j * 64 + o] : basis1[(j - 128) * 64 + o];
    Wc1T[idx] = f2bf(v);
  } else {
    int idx = (b - ZBLK - CURB - WTBLK - W1BLK) * 256 + tid; // 32*576, exact
    int c = idx / 576, j = idx - c * 576;
    float v = 0.f;
    if (c < 20) v = (j < 64) ? root2[j * 20 + c] : basis2[(j - 64) * 20 + c];
    Wc2T[idx] = f2bf(v);
  }
}

// ---------------------------------------------------------------------------
// CSR build — fixed-stride (MAXD per node): no cnt/scan kernels needed.
// ---------------------------------------------------------------------------
__global__ void deg_kernel(const int* __restrict__ ei, int* __restrict__ deg) {
  int gid = blockIdx.x * 256 + threadIdx.x;
  if (gid >= NE) return;
  int r = gid / EE, e = gid - r * EE;
  int d = ei[r * 2 * EE + EE + e];
  atomicAdd(&deg[r * NN + d], 1);
}

// rec = (r<<14)|src, esc = 1/max(deg,1); slot = atomic bump of cur[d]
__global__ void scatter_kernel(const int* __restrict__ ei,
                               const int* __restrict__ deg,
                               int* __restrict__ cur, int* __restrict__ rec,
                               float* __restrict__ esc) {
  int gid = blockIdx.x * 256 + threadIdx.x;
  if (gid >= NE) return;
  int r = gid / EE, e = gid - r * EE;
  int s = ei[r * 2 * EE + e];
  int d = ei[r * 2 * EE + EE + e];
  int p = atomicAdd(&cur[d], 1);
  if (p < MAXD) {
    rec[d * MAXD + p] = (r << 14) | s;
    esc[d * MAXD + p] = 1.0f / fmaxf((float)deg[r * NN + d], 1.0f);
  }
}

// ---------------------------------------------------------------------------
// gemm0 (round-1 shape, empirically best): tile M=32, N=128, BK=64; grid
// (313,4)=1252 blocks @ 40KB LDS -> 4/CU. 1-deep register prefetch, ONE
// barrier per K-step. (M=64/628-block + 2-deep regressed: compiler can't
// keep 2 sets live -> VGPR 68, loads sunk to stores, latency exposed.)
// ---------------------------------------------------------------------------
__global__ __launch_bounds__(256) void gemm0_mfma(
    const float* __restrict__ A, const unsigned short* __restrict__ Btw,
    float* __restrict__ xp) {
  __shared__ __align__(16) unsigned short Asb[2][32 * 64];    // 2 x 4 KB
  __shared__ __align__(16) unsigned short Bsb[2][128 * 64];   // 2 x 16 KB
  const int tid = threadIdx.x;
  const int m0 = blockIdx.x * 32;
  const int ks = blockIdx.y;
  const int wv = tid >> 6, lane = tid & 63;
  const int lrow = lane & 15, quad = lane >> 4;
  const int mt = wv >> 1;           // which 16-row half of the 32-row tile
  const int nh = (wv & 1) * 4;      // 4 n-tiles of 16 cols (64-col half)

  const int ar = tid >> 3, ag = tid & 7;
  int gra = m0 + ar; if (gra >= NN) gra = NN - 1;
  const float* Ap = &A[(size_t)gra * D0 + ks * 512 + ag * 4];
  const int asw = (ar & 7) << 4;
  const int aw0 = (ar * 128 + ((ag * 8) ^ asw)) >> 1;        // ushort idx
  const int aw1 = (ar * 128 + ((64 + ag * 8) ^ asw)) >> 1;

  const int br = tid >> 1, bh = tid & 1;
  const unsigned short* Bp = &Btw[(size_t)br * D0 + ks * 512 + bh * 8];
  const int bsw = (br & 7) << 4;
  int bw[4];
#pragma unroll
  for (int j = 0; j < 4; j++)
    bw[j] = (br * 128 + ((bh * 16 + j * 32) ^ bsw)) >> 1;

  float4 a0, a1;
  uint4 b0, b1, b2, b3;

#define G0_LOADG(c)                                  \
  { a0 = *(const float4*)(Ap + (c) * 64);            \
    a1 = *(const float4*)(Ap + (c) * 64 + 32);       \
    b0 = *(const uint4*)(Bp + (c) * 64);             \
    b1 = *(const uint4*)(Bp + (c) * 64 + 16);        \
    b2 = *(const uint4*)(Bp + (c) * 64 + 32);        \
    b3 = *(const uint4*)(Bp + (c) * 64 + 48); }

#define G0_STOREL(buf)                                                  \
  { uint2 p0, p1;                                                       \
    p0.x = pk2(a0.x, a0.y); p0.y = pk2(a0.z, a0.w);                     \
    p1.x = pk2(a1.x, a1.y); p1.y = pk2(a1.z, a1.w);                     \
    *(uint2*)&Asb[buf][aw0] = p0;                                       \
    *(uint2*)&Asb[buf][aw1] = p1;                                       \
    *(uint4*)&Bsb[buf][bw[0]] = b0;                                     \
    *(uint4*)&Bsb[buf][bw[1]] = b1;                                     \
    *(uint4*)&Bsb[buf][bw[2]] = b2;                                     \
    *(uint4*)&Bsb[buf][bw[3]] = b3; }

#define G0_COMPUTE(buf)                                                 \
  { const int arow = mt * 16 + lrow;                                    \
    const int aswz = (arow & 7) << 4;                                   \
    _Pragma("unroll")                                                   \
    for (int kk = 0; kk < 2; kk++) {                                    \
      short8 af = *(const short8*)&Asb[buf][(arow * 128 + ((quad * 16 + kk * 64) ^ aswz)) >> 1]; \
      _Pragma("unroll")                                                 \
      for (int nt = 0; nt < 4; nt++) {                                  \
        const int brow = (nh + nt) * 16 + lrow;                         \
        short8 bfr = *(const short8*)&Bsb[buf][(brow * 128 + ((quad * 16 + kk * 64) ^ ((brow & 7) << 4))) >> 1]; \
        acc[nt] = __builtin_amdgcn_mfma_f32_16x16x32_bf16(af, bfr, acc[nt], 0, 0, 0); \
      }                                                                 \
    } }

  float4e acc[4];
#pragma unroll
  for (int i = 0; i < 4; i++) { acc[i][0]=0.f; acc[i][1]=0.f; acc[i][2]=0.f; acc[i][3]=0.f; }

  G0_LOADG(0);
  G0_STOREL(0);
  __syncthreads();

#pragma unroll
  for (int c = 0; c < 8; c++) {
    if (c < 7) G0_LOADG(c + 1);
    G0_COMPUTE(c & 1);
    if (c < 7) G0_STOREL((c + 1) & 1);
    __syncthreads();
  }

#pragma unroll
  for (int nt = 0; nt < 4; nt++) {
    const int col = (nh + nt) * 16 + lrow;
#pragma unroll
    for (int r = 0; r < 4; r++) {
      const int row = m0 + mt * 16 + quad * 4 + r;
      if (row < NN)
        xp[(size_t)ks * (NN * D1) + (size_t)row * D1 + col] = acc[nt][r];
    }
  }
}

// xb = bf16(xp0+xp1+xp2+xp3)
__global__ void reduce_kernel(const float* __restrict__ xp,
                              unsigned short* __restrict__ xb) {
  int idx = (blockIdx.x * 256 + threadIdx.x) * 4;
  if (idx >= NN * D1) return;
  float4 a = *(const float4*)&xp[idx];
  float4 b = *(const float4*)&xp[NN * D1 + idx];
  float4 c = *(const float4*)&xp[2 * NN * D1 + idx];
  float4 d = *(const float4*)&xp[3 * NN * D1 + idx];
  ushort4 o;
  o.x = f2bf(a.x + b.x + c.x + d.x); o.y = f2bf(a.y + b.y + c.y + d.y);
  o.z = f2bf(a.z + b.z + c.z + d.z); o.w = f2bf(a.w + b.w + c.w + d.w);
  *(ushort4*)&xb[idx] = o;
}

// ---------------------------------------------------------------------------
// agg1e: A1b[n, b*128+i] = bf16( sum_{e->n} esc_e*comp1[r_e,b]*x[src_e,i] )
// ---------------------------------------------------------------------------
__global__ __launch_bounds__(256) void agg1e_kernel(
    const unsigned short* __restrict__ xb, const int* __restrict__ cur,
    const int* __restrict__ rec, const float* __restrict__ esc,
    const float* __restrict__ comp, unsigned short* __restrict__ A1b) {
  __shared__ float s_comp[RR * 8];
  const int tid = threadIdx.x;
  for (int i = tid; i < RR * 8; i += 256) s_comp[i] = comp[i];
  __syncthreads();
  const int wv = tid >> 6, lane = tid & 63;
  const int n = blockIdx.x * 4 + wv;
  if (n >= NN) return;
  float acc[8][2];
#pragma unroll
  for (int b = 0; b < 8; b++) { acc[b][0] = 0.f; acc[b][1] = 0.f; }
  int cnt = cur[n]; if (cnt > MAXD) cnt = MAXD;
  const int beg = n * MAXD, end = beg + cnt;
  int idx = beg;
  for (; idx + 3 < end; idx += 4) {
    int rc[4]; float sc[4]; unsigned int xv[4];
#pragma unroll
    for (int u = 0; u < 4; u++) {
      rc[u] = rec[idx + u];
      sc[u] = esc[idx + u];
    }
#pragma unroll
    for (int u = 0; u < 4; u++)
      xv[u] = *(const unsigned int*)&xb[(size_t)(rc[u] & 16383) * D1 + lane * 2];
#pragma unroll
    for (int u = 0; u < 4; u++) {
      const float* cb = &s_comp[(rc[u] >> 14) * 8];
      float x0 = __uint_as_float((xv[u] & 0xffffu) << 16);
      float x1 = __uint_as_float(xv[u] & 0xffff0000u);
#pragma unroll
      for (int b = 0; b < 8; b++) {
        float w = sc[u] * cb[b];
        acc[b][0] += w * x0;
        acc[b][1] += w * x1;
      }
    }
  }
  for (; idx < end; idx++) {
    int rc = rec[idx];
    float sc = esc[idx];
    unsigned int xv = *(const unsigned int*)&xb[(size_t)(rc & 16383) * D1 + lane * 2];
    const float* cb = &s_comp[(rc >> 14) * 8];
    float x0 = __uint_as_float((xv & 0xffffu) << 16);
    float x1 = __uint_as_float(xv & 0xffff0000u);
#pragma unroll
    for (int b = 0; b < 8; b++) {
      float w = sc * cb[b];
      acc[b][0] += w * x0;
      acc[b][1] += w * x1;
    }
  }
#pragma unroll
  for (int b = 0; b < 8; b++) {
    ushort2 o; o.x = f2bf(acc[b][0]); o.y = f2bf(acc[b][1]);
    *(ushort2*)&A1b[(size_t)n * 1024 + b * 128 + lane * 2] = o;
  }
}

// ---------------------------------------------------------------------------
// agg2e: A2b[n, b*64+i] = bf16( sum_{e->n} esc_e*comp2[r_e,b]*h[src_e,i] )
// ---------------------------------------------------------------------------
__global__ __launch_bounds__(256) void agg2e_kernel(
    const unsigned short* __restrict__ hb, const int* __restrict__ cur,
    const int* __restrict__ rec, const float* __restrict__ esc,
    const float* __restrict__ comp, unsigned short* __restrict__ A2b) {
  __shared__ float s_comp[RR * 8];
  const int tid = threadIdx.x;
  for (int i = tid; i < RR * 8; i += 256) s_comp[i] = comp[i];
  __syncthreads();
  const int wv = tid >> 6, lane = tid & 63;
  const int n = blockIdx.x * 4 + wv;
  if (n >= NN) return;
  float acc[8];
#pragma unroll
  for (int b = 0; b < 8; b++) acc[b] = 0.f;
  int cnt = cur[n]; if (cnt > MAXD) cnt = MAXD;
  const int beg = n * MAXD, end = beg + cnt;
  int idx = beg;
  for (; idx + 3 < end; idx += 4) {
    int rc[4]; float sc[4]; float hv[4];
#pragma unroll
    for (int u = 0; u < 4; u++) {
      rc[u] = rec[idx + u];
      sc[u] = esc[idx + u];
    }
#pragma unroll
    for (int u = 0; u < 4; u++)
      hv[u] = bf2f(hb[(size_t)(rc[u] & 16383) * D2 + lane]);
#pragma unroll
    for (int u = 0; u < 4; u++) {
      const float* cb = &s_comp[(rc[u] >> 14) * 8];
#pragma unroll
      for (int b = 0; b < 8; b++) acc[b] += sc[u] * cb[b] * hv[u];
    }
  }
  for (; idx < end; idx++) {
    int rc = rec[idx];
    float sc = esc[idx];
    float hv = bf2f(hb[(size_t)(rc & 16383) * D2 + lane]);
    const float* cb = &s_comp[(rc >> 14) * 8];
#pragma unroll
    for (int b = 0; b < 8; b++) acc[b] += sc * cb[b] * hv;
  }
#pragma unroll
  for (int b = 0; b < 8; b++)
    A2b[(size_t)n * 512 + b * 64 + lane] = f2bf(acc[b]);
}

// ---------------------------------------------------------------------------
// hlayer: hb = bf16(relu([xb|A1b](K=1152) @ Wc1T + bias1))
// REWRITTEN: tile M=32 x N=64, BK=64, 18 K-steps, ONE barrier per step
// (was 36 steps x 2 barriers each = 72 barriers -> 18). Double-buffered
// XOR-swizzled LDS (24 KB), 1-deep register prefetch. 313 blocks.
// ---------------------------------------------------------------------------
__global__ __launch_bounds__(256) void hlayer_mfma(
    const unsigned short* __restrict__ xb, const unsigned short* __restrict__ A1b,
    const unsigned short* __restrict__ Wt, const float* __restrict__ bias1,
    unsigned short* __restrict__ hb) {
  __shared__ __align__(16) unsigned short Asb[2][32 * 64];   // 8 KB
  __shared__ __align__(16) unsigned short Bsb[2][64 * 64];   // 16 KB
  const int tid = threadIdx.x;
  const int m0 = blockIdx.x * 32;
  const int wv = tid >> 6, lane = tid & 63;
  const int lrow = lane & 15, quad = lane >> 4;
  const int mt = wv >> 1, nb = wv & 1;    // wave: 16 rows x 32 cols

  // A staging: 32 rows x 64 K. ar=tid>>3, 8 bf16 (16B) at K-cols ac*8.
  const int ar = tid >> 3, ac = tid & 7;
  int gr = m0 + ar; if (gr >= NN) gr = NN - 1;
  const unsigned short* Ax = &xb[(size_t)gr * D1 + ac * 8];     // steps 0-1
  const unsigned short* Aa = &A1b[(size_t)gr * 1024 + ac * 8];  // steps 2-17
  const int asw = (ar & 7) << 4;
  const int aw = (ar * 128 + ((ac * 16) ^ asw)) >> 1;

  // B staging: 64 rows x 64 K. br=tid>>2, 16 bf16 (32B) at K-cols bq*16.
  const int br = tid >> 2, bq = tid & 3;
  const unsigned short* Bp = &Wt[(size_t)br * 1152 + bq * 16];
  const int bsw = (br & 7) << 4;
  const int bw0 = (br * 128 + ((bq * 32) ^ bsw)) >> 1;
  const int bw1 = (br * 128 + ((bq * 32 + 16) ^ bsw)) >> 1;

  uint4 ra, rb0, rb1;

#define H_LOADG(c)                                                       \
  { int kb = (c) * 64;                                                   \
    ra  = (kb < 128) ? *(const uint4*)(Ax + kb)                          \
                     : *(const uint4*)(Aa + (kb - 128));                 \
    rb0 = *(const uint4*)(Bp + kb);                                      \
    rb1 = *(const uint4*)(Bp + kb + 8); }

#define H_STOREL(buf)                                                    \
  { *(uint4*)&Asb[buf][aw]  = ra;                                        \
    *(uint4*)&Bsb[buf][bw0] = rb0;                                       \
    *(uint4*)&Bsb[buf][bw1] = rb1; }

#define H_COMPUTE(buf)                                                   \
  { const int arow = mt * 16 + lrow;                                     \
    const int aswz = (arow & 7) << 4;                                    \
    _Pragma("unroll")                                                    \
    for (int kk = 0; kk < 2; kk++) {                                     \
      short8 af = *(const short8*)&Asb[buf][(arow * 128 + ((quad * 16 + kk * 64) ^ aswz)) >> 1]; \
      _Pragma("unroll")                                                  \
      for (int nt = 0; nt < 2; nt++) {                                   \
        const int brow = nb * 32 + nt * 16 + lrow;                       \
        short8 bfr = *(const short8*)&Bsb[buf][(brow * 128 + ((quad * 16 + kk * 64) ^ ((brow & 7) << 4))) >> 1]; \
        acc[nt] = __builtin_amdgcn_mfma_f32_16x16x32_bf16(af, bfr, acc[nt], 0, 0, 0); \
      }                                                                  \
    } }

  float4e acc[2];
#pragma unroll
  for (int i = 0; i < 2; i++) { acc[i][0]=0.f; acc[i][1]=0.f; acc[i][2]=0.f; acc[i][3]=0.f; }

  H_LOADG(0);
  H_STOREL(0);
  __syncthreads();

#pragma unroll
  for (int c = 0; c < 18; c++) {
    if (c < 17) H_LOADG(c + 1);
    H_COMPUTE(c & 1);
    if (c < 17) H_STOREL((c + 1) & 1);
    __syncthreads();
  }

#pragma unroll
  for (int nt = 0; nt < 2; nt++) {
    int col = nb * 32 + nt * 16 + lrow;
    float bv = bias1[col];
#pragma unroll
    for (int r = 0; r < 4; r++) {
      int row = m0 + mt * 16 + quad * 4 + r;
      if (row < NN)
        hb[(size_t)row * D2 + col] = f2bf(fmaxf(acc[nt][r] + bv, 0.f));
    }
  }
}

// ---------------------------------------------------------------------------
// out: out = [hb|A2b](K=576) @ Wc2T + bias2
// REWRITTEN: tile M=32 x N=32, BK=64, 9 K-steps, ONE barrier per step
// (was 18 steps x 2 barriers = 36 -> 9). Double-buffered XOR-swizzled LDS
// (16 KB), 1-deep register prefetch. 313 blocks.
// ---------------------------------------------------------------------------
__global__ __launch_bounds__(256) void out_mfma(
    const unsigned short* __restrict__ hb, const unsigned short* __restrict__ A2b,
    const unsigned short* __restrict__ Wt, const float* __restrict__ bias2,
    float* __restrict__ out) {
  __shared__ __align__(16) unsigned short Asb[2][32 * 64];   // 8 KB
  __shared__ __align__(16) unsigned short Bsb[2][32 * 64];   // 8 KB
  const int tid = threadIdx.x;
  const int m0 = blockIdx.x * 32;
  const int wv = tid >> 6, lane = tid & 63;
  const int lrow = lane & 15, quad = lane >> 4;
  const int mt = wv >> 1, ntn = wv & 1;   // wave: 16 rows x 16 cols

  // A and B staging: each 32 rows x 64 K; every thread does 16B of each.
  const int ar = tid >> 3, ac = tid & 7;
  int gr = m0 + ar; if (gr >= NN) gr = NN - 1;
  const unsigned short* Ah = &hb[(size_t)gr * D2 + ac * 8];     // step 0
  const unsigned short* Aa = &A2b[(size_t)gr * 512 + ac * 8];   // steps 1-8
  const unsigned short* Bp = &Wt[(size_t)ar * 576 + ac * 8];
  const int asw = (ar & 7) << 4;
  const int aw = (ar * 128 + ((ac * 16) ^ asw)) >> 1;

  uint4 ra, rb;

#define O_LOADG(c)                                                       \
  { int kb = (c) * 64;                                                   \
    ra = (kb < 64) ? *(const uint4*)(Ah)                                 \
                   : *(const uint4*)(Aa + (kb - 64));                    \
    rb = *(const uint4*)(Bp + kb); }

#define O_STOREL(buf)                                                    \
  { *(uint4*)&Asb[buf][aw] = ra;                                         \
    *(uint4*)&Bsb[buf][aw] = rb; }

#define O_COMPUTE(buf)                                                   \
  { const int arow = mt * 16 + lrow;                                     \
    const int aswz = (arow & 7) << 4;                                    \
    const int brow = ntn * 16 + lrow;                                    \
    const int bswz = (brow & 7) << 4;                                    \
    _Pragma("unroll")                                                    \
    for (int kk = 0; kk < 2; kk++) {                                     \
      short8 af = *(const short8*)&Asb[buf][(arow * 128 + ((quad * 16 + kk * 64) ^ aswz)) >> 1]; \
      short8 bfr = *(const short8*)&Bsb[buf][(brow * 128 + ((quad * 16 + kk * 64) ^ bswz)) >> 1]; \
      acc = __builtin_amdgcn_mfma_f32_16x16x32_bf16(af, bfr, acc, 0, 0, 0); \
    } }

  float4e acc;
  acc[0]=0.f; acc[1]=0.f; acc[2]=0.f; acc[3]=0.f;

  O_LOADG(0);
  O_STOREL(0);
  __syncthreads();

#pragma unroll
  for (int c = 0; c < 9; c++) {
    if (c < 8) O_LOADG(c + 1);
    O_COMPUTE(c & 1);
    if (c < 8) O_STOREL((c + 1) & 1);
    __syncthreads();
  }

  int col = ntn * 16 + lrow;
  if (col < D3) {
    float bv = bias2[col];
#pragma unroll
    for (int r = 0; r < 4; r++) {
      int row = m0 + mt * 16 + quad * 4 + r;
      if (row < NN)
        out[(size_t)row * D3 + col] = acc[r] + bv;
    }
  }
}

// ---------------------------------------------------------------------------
extern "C" void kernel_launch(void* const* d_in, const int* in_sizes, int n_in,
                              void* d_out, int out_size, void* d_ws,
                              size_t ws_size, hipStream_t stream) {
  const float* x_drug = (const float*)d_in[0];
  const float* drug_w = (const float*)d_in[1];
  const int*   ei     = (const int*)d_in[2];
  const float* basis1 = (const float*)d_in[3];
  const float* comp1  = (const float*)d_in[4];
  const float* root1  = (const float*)d_in[5];
  const float* bias1  = (const float*)d_in[6];
  const float* basis2 = (const float*)d_in[7];
  const float* comp2  = (const float*)d_in[8];
  const float* root2  = (const float*)d_in[9];
  const float* bias2  = (const float*)d_in[10];
  float* out = (float*)d_out;

  float* ws = (float*)d_ws;
  int*   deg  = (int*)ws;                          // 1,000,000
  int*   cur  = deg + 1000000;                     // 10,016
  int*   rec  = cur + 10016;                       // 1,280,000 (NN*MAXD)
  float* esc  = (float*)(rec + NN * MAXD);         // 1,280,000
  unsigned short* xb   = (unsigned short*)(esc + NN * MAXD);       // 640,000 f
  unsigned short* hb   = (unsigned short*)((float*)xb + 640000);   // 320,000 f
  unsigned short* Btw  = (unsigned short*)((float*)hb + 320000);   // 131,072 f
  unsigned short* Wc1T = (unsigned short*)((float*)Btw + 131072);  // 36,864 f
  unsigned short* Wc2T = (unsigned short*)((float*)Wc1T + 36864);  // 9,216 f
  float* R1 = (float*)Wc2T + 9216;                 // 5,120,000 floats shared
  float* xp = R1;                                  // 4 x 1,280,000 fp32 partials
  unsigned short* A1b = (unsigned short*)R1;       // aliases xp (after reduce)
  unsigned short* A2b = (unsigned short*)R1;       // aliases A1b (after hlayer)

  // fused prep: zero deg/cur + all weight transposes (one dispatch)
  prep_kernel<<<ZBLK + CURB + WTBLK + W1BLK + W2BLK, 256, 0, stream>>>(
      drug_w, root1, basis1, root2, basis2, (int4*)deg, (int4*)cur,
      Btw, Wc1T, Wc2T);

  // CSR build: fixed-stride slots, no cnt/scan
  deg_kernel<<<(NE + 255) / 256, 256, 0, stream>>>(ei, deg);
  scatter_kernel<<<(NE + 255) / 256, 256, 0, stream>>>(ei, deg, cur, rec, esc);

  // x = x_drug @ drug_w (bf16 MFMA, K-split 4 + reduce)
  gemm0_mfma<<<dim3(313, 4), 256, 0, stream>>>(x_drug, Btw, xp);
  reduce_kernel<<<(NN * D1 / 4 + 255) / 256, 256, 0, stream>>>(xp, xb);

  // layer 1
  agg1e_kernel<<<(NN + 3) / 4, 256, 0, stream>>>(xb, cur, rec, esc, comp1, A1b);
  hlayer_mfma<<<(NN + 31) / 32, 256, 0, stream>>>(xb, A1b, Wc1T, bias1, hb);

  // layer 2
  agg2e_kernel<<<(NN + 3) / 4, 256, 0, stream>>>(hb, cur, rec, esc, comp2, A2b);
  out_mfma<<<(NN + 31) / 32, 256, 0, stream>>>(hb, A2b, Wc2T, bias2, out);
}

// Round 7
// 175.281 us; speedup vs baseline: 1.1120x; 1.0150x over previous
//
#include <hip/hip_runtime.h>

#define NN 10000    // nodes
#define RR 100      // relations
#define EE 5000     // edges per relation
#define D0 2048
#define D1 128
#define D2 64
#define D3 20
#define NE (RR*EE)  // 500000 edges total
#define MAXD 128    // fixed CSR stride per node (true max deg ~80, 11 sigma)

using short8  = __attribute__((ext_vector_type(8))) short;
using float4e = __attribute__((ext_vector_type(4))) float;

__device__ __forceinline__ unsigned short f2bf(float f) {
  unsigned int u = __float_as_uint(f);
  unsigned int r = u + 0x7fffu + ((u >> 16) & 1u);   // RNE
  return (unsigned short)(r >> 16);
}
__device__ __forceinline__ float bf2f(unsigned short u) {
  return __uint_as_float(((unsigned int)u) << 16);
}
__device__ __forceinline__ unsigned int pk2(float lo, float hi) {
  return ((unsigned int)f2bf(hi) << 16) | (unsigned int)f2bf(lo);
}

// ---------------------------------------------------------------------------
// prep: fused {zero deg, zero cur, wtrans, wc1t, wc2t} in one dispatch
// ---------------------------------------------------------------------------
#define ZBLK 977            // 250,000 int4 zeros (deg)
#define CURB 10             // 2,504 int4 zeros (cur)
#define WTBLK 1024          // 262,144 elems
#define W1BLK 288           // 73,728 elems
#define W2BLK 72            // 18,432 elems
__global__ __launch_bounds__(256) void prep_kernel(
    const float* __restrict__ W, const float* __restrict__ root1,
    const float* __restrict__ basis1, const float* __restrict__ root2,
    const float* __restrict__ basis2, int4* __restrict__ deg4,
    int4* __restrict__ cur4,
    unsigned short* __restrict__ Btw, unsigned short* __restrict__ Wc1T,
    unsigned short* __restrict__ Wc2T) {
  const int b = blockIdx.x, tid = threadIdx.x;
  if (b < ZBLK) {
    int i = b * 256 + tid;
    if (i < (NN * RR) / 4) deg4[i] = make_int4(0, 0, 0, 0);
  } else if (b < ZBLK + CURB) {
    int i = (b - ZBLK) * 256 + tid;
    if (i < 2504) cur4[i] = make_int4(0, 0, 0, 0);
  } else if (b < ZBLK + CURB + WTBLK) {
    int idx = (b - ZBLK - CURB) * 256 + tid;                 // 128*2048, exact
    int n = idx >> 11, k = idx & 2047;
    Btw[idx] = f2bf(W[(size_t)k * 128 + n]);
  } else if (b < ZBLK + CURB + WTBLK + W1BLK) {
    int idx = (b - ZBLK - CURB - WTBLK) * 256 + tid;         // 64*1152, exact
    int o = idx / 1152, j = idx - o * 1152;
    float v = (j < 128) ? root1[j * 64 + o] : basis1[(j - 128) * 64 + o];
    Wc1T[idx] = f2bf(v);
  } else {
    int idx = (b - ZBLK - CURB - WTBLK - W1BLK) * 256 + tid; // 32*576, exact
    int c = idx / 576, j = idx - c * 576;
    float v = 0.f;
    if (c < 20) v = (j < 64) ? root2[j * 20 + c] : basis2[(j - 64) * 20 + c];
    Wc2T[idx] = f2bf(v);
  }
}

// ---------------------------------------------------------------------------
// CSR build — fixed-stride (MAXD per node): no cnt/scan kernels needed.
// ---------------------------------------------------------------------------
__global__ void deg_kernel(const int* __restrict__ ei, int* __restrict__ deg) {
  int gid = blockIdx.x * 256 + threadIdx.x;
  if (gid >= NE) return;
  int r = gid / EE, e = gid - r * EE;
  int d = ei[r * 2 * EE + EE + e];
  atomicAdd(&deg[r * NN + d], 1);
}

// rec = (r<<14)|src, esc = 1/max(deg,1); slot = atomic bump of cur[d]
__global__ void scatter_kernel(const int* __restrict__ ei,
                               const int* __restrict__ deg,
                               int* __restrict__ cur, int* __restrict__ rec,
                               float* __restrict__ esc) {
  int gid = blockIdx.x * 256 + threadIdx.x;
  if (gid >= NE) return;
  int r = gid / EE, e = gid - r * EE;
  int s = ei[r * 2 * EE + e];
  int d = ei[r * 2 * EE + EE + e];
  int p = atomicAdd(&cur[d], 1);
  if (p < MAXD) {
    rec[d * MAXD + p] = (r << 14) | s;
    esc[d * MAXD + p] = 1.0f / fmaxf((float)deg[r * NN + d], 1.0f);
  }
}

// ---------------------------------------------------------------------------
// gemm0: tile M=32, N=128, BK=64; grid (313,4)=1252 blocks @ 40KB LDS ->
// 4/CU. 1-deep register prefetch, ONE barrier per K-step.
// sched_barrier(0) after the load issue PINS the prefetch: round-5 evidence
// (VGPR_Count=64/68 with 32 acc regs) shows hipcc was sinking the "prefetch"
// loads to just before the LDS store, exposing full HBM latency every step.
// ---------------------------------------------------------------------------
__global__ __launch_bounds__(256) void gemm0_mfma(
    const float* __restrict__ A, const unsigned short* __restrict__ Btw,
    float* __restrict__ xp) {
  __shared__ __align__(16) unsigned short Asb[2][32 * 64];    // 2 x 4 KB
  __shared__ __align__(16) unsigned short Bsb[2][128 * 64];   // 2 x 16 KB
  const int tid = threadIdx.x;
  const int m0 = blockIdx.x * 32;
  const int ks = blockIdx.y;
  const int wv = tid >> 6, lane = tid & 63;
  const int lrow = lane & 15, quad = lane >> 4;
  const int mt = wv >> 1;           // which 16-row half of the 32-row tile
  const int nh = (wv & 1) * 4;      // 4 n-tiles of 16 cols (64-col half)

  const int ar = tid >> 3, ag = tid & 7;
  int gra = m0 + ar; if (gra >= NN) gra = NN - 1;
  const float* Ap = &A[(size_t)gra * D0 + ks * 512 + ag * 4];
  const int asw = (ar & 7) << 4;
  const int aw0 = (ar * 128 + ((ag * 8) ^ asw)) >> 1;        // ushort idx
  const int aw1 = (ar * 128 + ((64 + ag * 8) ^ asw)) >> 1;

  const int br = tid >> 1, bh = tid & 1;
  const unsigned short* Bp = &Btw[(size_t)br * D0 + ks * 512 + bh * 8];
  const int bsw = (br & 7) << 4;
  int bw[4];
#pragma unroll
  for (int j = 0; j < 4; j++)
    bw[j] = (br * 128 + ((bh * 16 + j * 32) ^ bsw)) >> 1;

  float4 a0, a1;
  uint4 b0, b1, b2, b3;

#define G0_LOADG(c)                                  \
  { a0 = *(const float4*)(Ap + (c) * 64);            \
    a1 = *(const float4*)(Ap + (c) * 64 + 32);       \
    b0 = *(const uint4*)(Bp + (c) * 64);             \
    b1 = *(const uint4*)(Bp + (c) * 64 + 16);        \
    b2 = *(const uint4*)(Bp + (c) * 64 + 32);        \
    b3 = *(const uint4*)(Bp + (c) * 64 + 48); }

#define G0_STOREL(buf)                                                  \
  { uint2 p0, p1;                                                       \
    p0.x = pk2(a0.x, a0.y); p0.y = pk2(a0.z, a0.w);                     \
    p1.x = pk2(a1.x, a1.y); p1.y = pk2(a1.z, a1.w);                     \
    *(uint2*)&Asb[buf][aw0] = p0;                                       \
    *(uint2*)&Asb[buf][aw1] = p1;                                       \
    *(uint4*)&Bsb[buf][bw[0]] = b0;                                     \
    *(uint4*)&Bsb[buf][bw[1]] = b1;                                     \
    *(uint4*)&Bsb[buf][bw[2]] = b2;                                     \
    *(uint4*)&Bsb[buf][bw[3]] = b3; }

#define G0_COMPUTE(buf)                                                 \
  { const int arow = mt * 16 + lrow;                                    \
    const int aswz = (arow & 7) << 4;                                   \
    _Pragma("unroll")                                                   \
    for (int kk = 0; kk < 2; kk++) {                                    \
      short8 af = *(const short8*)&Asb[buf][(arow * 128 + ((quad * 16 + kk * 64) ^ aswz)) >> 1]; \
      _Pragma("unroll")                                                 \
      for (int nt = 0; nt < 4; nt++) {                                  \
        const int brow = (nh + nt) * 16 + lrow;                         \
        short8 bfr = *(const short8*)&Bsb[buf][(brow * 128 + ((quad * 16 + kk * 64) ^ ((brow & 7) << 4))) >> 1]; \
        acc[nt] = __builtin_amdgcn_mfma_f32_16x16x32_bf16(af, bfr, acc[nt], 0, 0, 0); \
      }                                                                 \
    } }

  float4e acc[4];
#pragma unroll
  for (int i = 0; i < 4; i++) { acc[i][0]=0.f; acc[i][1]=0.f; acc[i][2]=0.f; acc[i][3]=0.f; }

  G0_LOADG(0);
  G0_STOREL(0);
  __syncthreads();

#pragma unroll
  for (int c = 0; c < 8; c++) {
    if (c < 7) {
      G0_LOADG(c + 1);
      __builtin_amdgcn_sched_barrier(0);   // pin: loads issue BEFORE compute
    }
    G0_COMPUTE(c & 1);
    if (c < 7) G0_STOREL((c + 1) & 1);
    __syncthreads();
  }

#pragma unroll
  for (int nt = 0; nt < 4; nt++) {
    const int col = (nh + nt) * 16 + lrow;
#pragma unroll
    for (int r = 0; r < 4; r++) {
      const int row = m0 + mt * 16 + quad * 4 + r;
      if (row < NN)
        xp[(size_t)ks * (NN * D1) + (size_t)row * D1 + col] = acc[nt][r];
    }
  }
}

// xb = bf16(xp0+xp1+xp2+xp3)
__global__ void reduce_kernel(const float* __restrict__ xp,
                              unsigned short* __restrict__ xb) {
  int idx = (blockIdx.x * 256 + threadIdx.x) * 4;
  if (idx >= NN * D1) return;
  float4 a = *(const float4*)&xp[idx];
  float4 b = *(const float4*)&xp[NN * D1 + idx];
  float4 c = *(const float4*)&xp[2 * NN * D1 + idx];
  float4 d = *(const float4*)&xp[3 * NN * D1 + idx];
  ushort4 o;
  o.x = f2bf(a.x + b.x + c.x + d.x); o.y = f2bf(a.y + b.y + c.y + d.y);
  o.z = f2bf(a.z + b.z + c.z + d.z); o.w = f2bf(a.w + b.w + c.w + d.w);
  *(ushort4*)&xb[idx] = o;
}

// ---------------------------------------------------------------------------
// agg1e: A1b[n, b*128+i] = bf16( sum_{e->n} esc_e*comp1[r_e,b]*x[src_e,i] )
// ---------------------------------------------------------------------------
__global__ __launch_bounds__(256) void agg1e_kernel(
    const unsigned short* __restrict__ xb, const int* __restrict__ cur,
    const int* __restrict__ rec, const float* __restrict__ esc,
    const float* __restrict__ comp, unsigned short* __restrict__ A1b) {
  __shared__ float s_comp[RR * 8];
  const int tid = threadIdx.x;
  for (int i = tid; i < RR * 8; i += 256) s_comp[i] = comp[i];
  __syncthreads();
  const int wv = tid >> 6, lane = tid & 63;
  const int n = blockIdx.x * 4 + wv;
  if (n >= NN) return;
  float acc[8][2];
#pragma unroll
  for (int b = 0; b < 8; b++) { acc[b][0] = 0.f; acc[b][1] = 0.f; }
  int cnt = cur[n]; if (cnt > MAXD) cnt = MAXD;
  const int beg = n * MAXD, end = beg + cnt;
  int idx = beg;
  for (; idx + 3 < end; idx += 4) {
    int rc[4]; float sc[4]; unsigned int xv[4];
#pragma unroll
    for (int u = 0; u < 4; u++) {
      rc[u] = rec[idx + u];
      sc[u] = esc[idx + u];
    }
#pragma unroll
    for (int u = 0; u < 4; u++)
      xv[u] = *(const unsigned int*)&xb[(size_t)(rc[u] & 16383) * D1 + lane * 2];
#pragma unroll
    for (int u = 0; u < 4; u++) {
      const float* cb = &s_comp[(rc[u] >> 14) * 8];
      float x0 = __uint_as_float((xv[u] & 0xffffu) << 16);
      float x1 = __uint_as_float(xv[u] & 0xffff0000u);
#pragma unroll
      for (int b = 0; b < 8; b++) {
        float w = sc[u] * cb[b];
        acc[b][0] += w * x0;
        acc[b][1] += w * x1;
      }
    }
  }
  for (; idx < end; idx++) {
    int rc = rec[idx];
    float sc = esc[idx];
    unsigned int xv = *(const unsigned int*)&xb[(size_t)(rc & 16383) * D1 + lane * 2];
    const float* cb = &s_comp[(rc >> 14) * 8];
    float x0 = __uint_as_float((xv & 0xffffu) << 16);
    float x1 = __uint_as_float(xv & 0xffff0000u);
#pragma unroll
    for (int b = 0; b < 8; b++) {
      float w = sc * cb[b];
      acc[b][0] += w * x0;
      acc[b][1] += w * x1;
    }
  }
#pragma unroll
  for (int b = 0; b < 8; b++) {
    ushort2 o; o.x = f2bf(acc[b][0]); o.y = f2bf(acc[b][1]);
    *(ushort2*)&A1b[(size_t)n * 1024 + b * 128 + lane * 2] = o;
  }
}

// ---------------------------------------------------------------------------
// agg2e: A2b[n, b*64+i] = bf16( sum_{e->n} esc_e*comp2[r_e,b]*h[src_e,i] )
// ---------------------------------------------------------------------------
__global__ __launch_bounds__(256) void agg2e_kernel(
    const unsigned short* __restrict__ hb, const int* __restrict__ cur,
    const int* __restrict__ rec, const float* __restrict__ esc,
    const float* __restrict__ comp, unsigned short* __restrict__ A2b) {
  __shared__ float s_comp[RR * 8];
  const int tid = threadIdx.x;
  for (int i = tid; i < RR * 8; i += 256) s_comp[i] = comp[i];
  __syncthreads();
  const int wv = tid >> 6, lane = tid & 63;
  const int n = blockIdx.x * 4 + wv;
  if (n >= NN) return;
  float acc[8];
#pragma unroll
  for (int b = 0; b < 8; b++) acc[b] = 0.f;
  int cnt = cur[n]; if (cnt > MAXD) cnt = MAXD;
  const int beg = n * MAXD, end = beg + cnt;
  int idx = beg;
  for (; idx + 3 < end; idx += 4) {
    int rc[4]; float sc[4]; float hv[4];
#pragma unroll
    for (int u = 0; u < 4; u++) {
      rc[u] = rec[idx + u];
      sc[u] = esc[idx + u];
    }
#pragma unroll
    for (int u = 0; u < 4; u++)
      hv[u] = bf2f(hb[(size_t)(rc[u] & 16383) * D2 + lane]);
#pragma unroll
    for (int u = 0; u < 4; u++) {
      const float* cb = &s_comp[(rc[u] >> 14) * 8];
#pragma unroll
      for (int b = 0; b < 8; b++) acc[b] += sc[u] * cb[b] * hv[u];
    }
  }
  for (; idx < end; idx++) {
    int rc = rec[idx];
    float sc = esc[idx];
    float hv = bf2f(hb[(size_t)(rc & 16383) * D2 + lane]);
    const float* cb = &s_comp[(rc >> 14) * 8];
#pragma unroll
    for (int b = 0; b < 8; b++) acc[b] += sc * cb[b] * hv;
  }
#pragma unroll
  for (int b = 0; b < 8; b++)
    A2b[(size_t)n * 512 + b * 64 + lane] = f2bf(acc[b]);
}

// ---------------------------------------------------------------------------
// hlayer: hb = bf16(relu([xb|A1b](K=1152) @ Wc1T + bias1))
// tile M=32 x N=64, BK=64, 18 K-steps, ONE barrier per step, pinned prefetch.
// ---------------------------------------------------------------------------
__global__ __launch_bounds__(256) void hlayer_mfma(
    const unsigned short* __restrict__ xb, const unsigned short* __restrict__ A1b,
    const unsigned short* __restrict__ Wt, const float* __restrict__ bias1,
    unsigned short* __restrict__ hb) {
  __shared__ __align__(16) unsigned short Asb[2][32 * 64];   // 8 KB
  __shared__ __align__(16) unsigned short Bsb[2][64 * 64];   // 16 KB
  const int tid = threadIdx.x;
  const int m0 = blockIdx.x * 32;
  const int wv = tid >> 6, lane = tid & 63;
  const int lrow = lane & 15, quad = lane >> 4;
  const int mt = wv >> 1, nb = wv & 1;    // wave: 16 rows x 32 cols

  const int ar = tid >> 3, ac = tid & 7;
  int gr = m0 + ar; if (gr >= NN) gr = NN - 1;
  const unsigned short* Ax = &xb[(size_t)gr * D1 + ac * 8];     // steps 0-1
  const unsigned short* Aa = &A1b[(size_t)gr * 1024 + ac * 8];  // steps 2-17
  const int asw = (ar & 7) << 4;
  const int aw = (ar * 128 + ((ac * 16) ^ asw)) >> 1;

  const int br = tid >> 2, bq = tid & 3;
  const unsigned short* Bp = &Wt[(size_t)br * 1152 + bq * 16];
  const int bsw = (br & 7) << 4;
  const int bw0 = (br * 128 + ((bq * 32) ^ bsw)) >> 1;
  const int bw1 = (br * 128 + ((bq * 32 + 16) ^ bsw)) >> 1;

  uint4 ra, rb0, rb1;

#define H_LOADG(c)                                                       \
  { int kb = (c) * 64;                                                   \
    ra  = (kb < 128) ? *(const uint4*)(Ax + kb)                          \
                     : *(const uint4*)(Aa + (kb - 128));                 \
    rb0 = *(const uint4*)(Bp + kb);                                      \
    rb1 = *(const uint4*)(Bp + kb + 8); }

#define H_STOREL(buf)                                                    \
  { *(uint4*)&Asb[buf][aw]  = ra;                                        \
    *(uint4*)&Bsb[buf][bw0] = rb0;                                       \
    *(uint4*)&Bsb[buf][bw1] = rb1; }

#define H_COMPUTE(buf)                                                   \
  { const int arow = mt * 16 + lrow;                                     \
    const int aswz = (arow & 7) << 4;                                    \
    _Pragma("unroll")                                                    \
    for (int kk = 0; kk < 2; kk++) {                                     \
      short8 af = *(const short8*)&Asb[buf][(arow * 128 + ((quad * 16 + kk * 64) ^ aswz)) >> 1]; \
      _Pragma("unroll")                                                  \
      for (int nt = 0; nt < 2; nt++) {                                   \
        const int brow = nb * 32 + nt * 16 + lrow;                       \
        short8 bfr = *(const short8*)&Bsb[buf][(brow * 128 + ((quad * 16 + kk * 64) ^ ((brow & 7) << 4))) >> 1]; \
        acc[nt] = __builtin_amdgcn_mfma_f32_16x16x32_bf16(af, bfr, acc[nt], 0, 0, 0); \
      }                                                                  \
    } }

  float4e acc[2];
#pragma unroll
  for (int i = 0; i < 2; i++) { acc[i][0]=0.f; acc[i][1]=0.f; acc[i][2]=0.f; acc[i][3]=0.f; }

  H_LOADG(0);
  H_STOREL(0);
  __syncthreads();

#pragma unroll
  for (int c = 0; c < 18; c++) {
    if (c < 17) {
      H_LOADG(c + 1);
      __builtin_amdgcn_sched_barrier(0);   // pin prefetch before compute
    }
    H_COMPUTE(c & 1);
    if (c < 17) H_STOREL((c + 1) & 1);
    __syncthreads();
  }

#pragma unroll
  for (int nt = 0; nt < 2; nt++) {
    int col = nb * 32 + nt * 16 + lrow;
    float bv = bias1[col];
#pragma unroll
    for (int r = 0; r < 4; r++) {
      int row = m0 + mt * 16 + quad * 4 + r;
      if (row < NN)
        hb[(size_t)row * D2 + col] = f2bf(fmaxf(acc[nt][r] + bv, 0.f));
    }
  }
}

// ---------------------------------------------------------------------------
// out: out = [hb|A2b](K=576) @ Wc2T + bias2
// tile M=32 x N=32, BK=64, 9 K-steps, ONE barrier per step, pinned prefetch.
// ---------------------------------------------------------------------------
__global__ __launch_bounds__(256) void out_mfma(
    const unsigned short* __restrict__ hb, const unsigned short* __restrict__ A2b,
    const unsigned short* __restrict__ Wt, const float* __restrict__ bias2,
    float* __restrict__ out) {
  __shared__ __align__(16) unsigned short Asb[2][32 * 64];   // 8 KB
  __shared__ __align__(16) unsigned short Bsb[2][32 * 64];   // 8 KB
  const int tid = threadIdx.x;
  const int m0 = blockIdx.x * 32;
  const int wv = tid >> 6, lane = tid & 63;
  const int lrow = lane & 15, quad = lane >> 4;
  const int mt = wv >> 1, ntn = wv & 1;   // wave: 16 rows x 16 cols

  const int ar = tid >> 3, ac = tid & 7;
  int gr = m0 + ar; if (gr >= NN) gr = NN - 1;
  const unsigned short* Ah = &hb[(size_t)gr * D2 + ac * 8];     // step 0
  const unsigned short* Aa = &A2b[(size_t)gr * 512 + ac * 8];   // steps 1-8
  const unsigned short* Bp = &Wt[(size_t)ar * 576 + ac * 8];
  const int asw = (ar & 7) << 4;
  const int aw = (ar * 128 + ((ac * 16) ^ asw)) >> 1;

  uint4 ra, rb;

#define O_LOADG(c)                                                       \
  { int kb = (c) * 64;                                                   \
    ra = (kb < 64) ? *(const uint4*)(Ah)                                 \
                   : *(const uint4*)(Aa + (kb - 64));                    \
    rb = *(const uint4*)(Bp + kb); }

#define O_STOREL(buf)                                                    \
  { *(uint4*)&Asb[buf][aw] = ra;                                         \
    *(uint4*)&Bsb[buf][aw] = rb; }

#define O_COMPUTE(buf)                                                   \
  { const int arow = mt * 16 + lrow;                                     \
    const int aswz = (arow & 7) << 4;                                    \
    const int brow = ntn * 16 + lrow;                                    \
    const int bswz = (brow & 7) << 4;                                    \
    _Pragma("unroll")                                                    \
    for (int kk = 0; kk < 2; kk++) {                                     \
      short8 af = *(const short8*)&Asb[buf][(arow * 128 + ((quad * 16 + kk * 64) ^ aswz)) >> 1]; \
      short8 bfr = *(const short8*)&Bsb[buf][(brow * 128 + ((quad * 16 + kk * 64) ^ bswz)) >> 1]; \
      acc = __builtin_amdgcn_mfma_f32_16x16x32_bf16(af, bfr, acc, 0, 0, 0); \
    } }

  float4e acc;
  acc[0]=0.f; acc[1]=0.f; acc[2]=0.f; acc[3]=0.f;

  O_LOADG(0);
  O_STOREL(0);
  __syncthreads();

#pragma unroll
  for (int c = 0; c < 9; c++) {
    if (c < 8) {
      O_LOADG(c + 1);
      __builtin_amdgcn_sched_barrier(0);   // pin prefetch before compute
    }
    O_COMPUTE(c & 1);
    if (c < 8) O_STOREL((c + 1) & 1);
    __syncthreads();
  }

  int col = ntn * 16 + lrow;
  if (col < D3) {
    float bv = bias2[col];
#pragma unroll
    for (int r = 0; r < 4; r++) {
      int row = m0 + mt * 16 + quad * 4 + r;
      if (row < NN)
        out[(size_t)row * D3 + col] = acc[r] + bv;
    }
  }
}

// ---------------------------------------------------------------------------
extern "C" void kernel_launch(void* const* d_in, const int* in_sizes, int n_in,
                              void* d_out, int out_size, void* d_ws,
                              size_t ws_size, hipStream_t stream) {
  const float* x_drug = (const float*)d_in[0];
  const float* drug_w = (const float*)d_in[1];
  const int*   ei     = (const int*)d_in[2];
  const float* basis1 = (const float*)d_in[3];
  const float* comp1  = (const float*)d_in[4];
  const float* root1  = (const float*)d_in[5];
  const float* bias1  = (const float*)d_in[6];
  const float* basis2 = (const float*)d_in[7];
  const float* comp2  = (const float*)d_in[8];
  const float* root2  = (const float*)d_in[9];
  const float* bias2  = (const float*)d_in[10];
  float* out = (float*)d_out;

  float* ws = (float*)d_ws;
  int*   deg  = (int*)ws;                          // 1,000,000
  int*   cur  = deg + 1000000;                     // 10,016
  int*   rec  = cur + 10016;                       // 1,280,000 (NN*MAXD)
  float* esc  = (float*)(rec + NN * MAXD);         // 1,280,000
  unsigned short* xb   = (unsigned short*)(esc + NN * MAXD);       // 640,000 f
  unsigned short* hb   = (unsigned short*)((float*)xb + 640000);   // 320,000 f
  unsigned short* Btw  = (unsigned short*)((float*)hb + 320000);   // 131,072 f
  unsigned short* Wc1T = (unsigned short*)((float*)Btw + 131072);  // 36,864 f
  unsigned short* Wc2T = (unsigned short*)((float*)Wc1T + 36864);  // 9,216 f
  float* R1 = (float*)Wc2T + 9216;                 // 5,120,000 floats shared
  float* xp = R1;                                  // 4 x 1,280,000 fp32 partials
  unsigned short* A1b = (unsigned short*)R1;       // aliases xp (after reduce)
  unsigned short* A2b = (unsigned short*)R1;       // aliases A1b (after hlayer)

  // fused prep: zero deg/cur + all weight transposes (one dispatch)
  prep_kernel<<<ZBLK + CURB + WTBLK + W1BLK + W2BLK, 256, 0, stream>>>(
      drug_w, root1, basis1, root2, basis2, (int4*)deg, (int4*)cur,
      Btw, Wc1T, Wc2T);

  // CSR build: fixed-stride slots, no cnt/scan
  deg_kernel<<<(NE + 255) / 256, 256, 0, stream>>>(ei, deg);
  scatter_kernel<<<(NE + 255) / 256, 256, 0, stream>>>(ei, deg, cur, rec, esc);

  // x = x_drug @ drug_w (bf16 MFMA, K-split 4 + reduce)
  gemm0_mfma<<<dim3(313, 4), 256, 0, stream>>>(x_drug, Btw, xp);
  reduce_kernel<<<(NN * D1 / 4 + 255) / 256, 256, 0, stream>>>(xp, xb);

  // layer 1
  agg1e_kernel<<<(NN + 3) / 4, 256, 0, stream>>>(xb, cur, rec, esc, comp1, A1b);
  hlayer_mfma<<<(NN + 31) / 32, 256, 0, stream>>>(xb, A1b, Wc1T, bias1, hb);

  // layer 2
  agg2e_kernel<<<(NN + 3) / 4, 256, 0, stream>>>(hb, cur, rec, esc, comp2, A2b);
  out_mfma<<<(NN + 31) / 32, 256, 0, stream>>>(hb, A2b, Wc2T, bias2, out);
}

// Round 8
// 174.587 us; speedup vs baseline: 1.1164x; 1.0040x over previous
//
#include <hip/hip_runtime.h>

#define NN 10000    // nodes
#define RR 100      // relations
#define EE 5000     // edges per relation
#define D0 2048
#define D1 128
#define D2 64
#define D3 20
#define NE (RR*EE)  // 500000 edges total
#define MAXD 128    // fixed CSR stride per node (true max deg ~80, 11 sigma)

using short8  = __attribute__((ext_vector_type(8))) short;
using float4e = __attribute__((ext_vector_type(4))) float;

typedef const __attribute__((address_space(1))) void g_void;
typedef __attribute__((address_space(3))) void l_void;

__device__ __forceinline__ unsigned short f2bf(float f) {
  unsigned int u = __float_as_uint(f);
  unsigned int r = u + 0x7fffu + ((u >> 16) & 1u);   // RNE
  return (unsigned short)(r >> 16);
}
__device__ __forceinline__ float bf2f(unsigned short u) {
  return __uint_as_float(((unsigned int)u) << 16);
}
__device__ __forceinline__ unsigned int pk2(float lo, float hi) {
  return ((unsigned int)f2bf(hi) << 16) | (unsigned int)f2bf(lo);
}

// ---------------------------------------------------------------------------
// prep: fused {zero deg, zero cur, wtrans, wc1t, wc2t} in one dispatch
// ---------------------------------------------------------------------------
#define ZBLK 977            // 250,000 int4 zeros (deg)
#define CURB 10             // 2,504 int4 zeros (cur)
#define WTBLK 1024          // 262,144 elems
#define W1BLK 288           // 73,728 elems
#define W2BLK 72            // 18,432 elems
__global__ __launch_bounds__(256) void prep_kernel(
    const float* __restrict__ W, const float* __restrict__ root1,
    const float* __restrict__ basis1, const float* __restrict__ root2,
    const float* __restrict__ basis2, int4* __restrict__ deg4,
    int4* __restrict__ cur4,
    unsigned short* __restrict__ Btw, unsigned short* __restrict__ Wc1T,
    unsigned short* __restrict__ Wc2T) {
  const int b = blockIdx.x, tid = threadIdx.x;
  if (b < ZBLK) {
    int i = b * 256 + tid;
    if (i < (NN * RR) / 4) deg4[i] = make_int4(0, 0, 0, 0);
  } else if (b < ZBLK + CURB) {
    int i = (b - ZBLK) * 256 + tid;
    if (i < 2504) cur4[i] = make_int4(0, 0, 0, 0);
  } else if (b < ZBLK + CURB + WTBLK) {
    int idx = (b - ZBLK - CURB) * 256 + tid;                 // 128*2048, exact
    int n = idx >> 11, k = idx & 2047;
    Btw[idx] = f2bf(W[(size_t)k * 128 + n]);
  } else if (b < ZBLK + CURB + WTBLK + W1BLK) {
    int idx = (b - ZBLK - CURB - WTBLK) * 256 + tid;         // 64*1152, exact
    int o = idx / 1152, j = idx - o * 1152;
    float v = (j < 128) ? root1[j * 64 + o] : basis1[(j - 128) * 64 + o];
    Wc1T[idx] = f2bf(v);
  } else {
    int idx = (b - ZBLK - CURB - WTBLK - W1BLK) * 256 + tid; // 32*576, exact
    int c = idx / 576, j = idx - c * 576;
    float v = 0.f;
    if (c < 20) v = (j < 64) ? root2[j * 20 + c] : basis2[(j - 64) * 20 + c];
    Wc2T[idx] = f2bf(v);
  }
}

// ---------------------------------------------------------------------------
// CSR build — fixed-stride (MAXD per node): no cnt/scan kernels needed.
// ---------------------------------------------------------------------------
__global__ void deg_kernel(const int* __restrict__ ei, int* __restrict__ deg) {
  int gid = blockIdx.x * 256 + threadIdx.x;
  if (gid >= NE) return;
  int r = gid / EE, e = gid - r * EE;
  int d = ei[r * 2 * EE + EE + e];
  atomicAdd(&deg[r * NN + d], 1);
}

// rec = (r<<14)|src, esc = 1/max(deg,1); slot = atomic bump of cur[d]
__global__ void scatter_kernel(const int* __restrict__ ei,
                               const int* __restrict__ deg,
                               int* __restrict__ cur, int* __restrict__ rec,
                               float* __restrict__ esc) {
  int gid = blockIdx.x * 256 + threadIdx.x;
  if (gid >= NE) return;
  int r = gid / EE, e = gid - r * EE;
  int s = ei[r * 2 * EE + e];
  int d = ei[r * 2 * EE + EE + e];
  int p = atomicAdd(&cur[d], 1);
  if (p < MAXD) {
    rec[d * MAXD + p] = (r << 14) | s;
    esc[d * MAXD + p] = 1.0f / fmaxf((float)deg[r * NN + d], 1.0f);
  }
}

// ---------------------------------------------------------------------------
// gemm0: tile M=32, N=128, BK=64; grid (313,4)=1252 blocks @ 40KB LDS, 4/CU.
// B staging now via global_load_lds width=16 (fire-and-forget, no VGPR
// round-trip — Common-mistake #1 / m151). LDS dest is LINEAR per wave
// (base + lane*16B); the XOR swizzle is preserved by PRE-SWIZZLING the
// per-lane GLOBAL source: lane l fetches global 16B-chunk (l&7)^(l>>3) of
// its row, so LDS[row][chunk C] = global chunk C^(row&7) — identical
// content to the old ds_write path; read side unchanged. A stays on the
// reg path (fp32->bf16 pack), pinned with sched_barrier(0).
// ---------------------------------------------------------------------------
__global__ __launch_bounds__(256) void gemm0_mfma(
    const float* __restrict__ A, const unsigned short* __restrict__ Btw,
    float* __restrict__ xp) {
  __shared__ __align__(16) unsigned short Asb[2][32 * 64];    // 2 x 4 KB
  __shared__ __align__(16) unsigned short Bsb[2][128 * 64];   // 2 x 16 KB
  const int tid = threadIdx.x;
  const int m0 = blockIdx.x * 32;
  const int ks = blockIdx.y;
  const int wv = tid >> 6, lane = tid & 63;
  const int lrow = lane & 15, quad = lane >> 4;
  const int mt = wv >> 1;           // which 16-row half of the 32-row tile
  const int nh = (wv & 1) * 4;      // 4 n-tiles of 16 cols (64-col half)

  // A staging (reg path): row ar = tid>>3, piece ag = tid&7
  const int ar = tid >> 3, ag = tid & 7;
  int gra = m0 + ar; if (gra >= NN) gra = NN - 1;
  const float* Ap = &A[(size_t)gra * D0 + ks * 512 + ag * 4];
  const int asw = (ar & 7) << 4;
  const int aw0 = (ar * 128 + ((ag * 8) ^ asw)) >> 1;        // ushort idx
  const int aw1 = (ar * 128 + ((64 + ag * 8) ^ asw)) >> 1;

  // B staging (global_load_lds): wave w, issue i, lane l ->
  //   LDS row w*32+i*8+(l>>3), chunk l&7 ; global chunk (l&7)^(l>>3)
  const int rowB = wv * 32 + (lane >> 3);
  const int gch  = (lane & 7) ^ (lane >> 3);
  const unsigned short* BgBase = &Btw[(size_t)rowB * D0 + ks * 512 + gch * 8];
  const int ldsB = wv * 2048;   // ushort idx of this wave's 4KB region

  float4 a0, a1;

#define G0_LOADB(buf, c)                                                     \
  { _Pragma("unroll")                                                        \
    for (int i = 0; i < 4; i++) {                                            \
      __builtin_amdgcn_global_load_lds(                                      \
          (g_void*)(BgBase + (size_t)i * 8 * D0 + (c) * 64),                 \
          (l_void*)&Bsb[buf][ldsB + i * 512], 16, 0, 0);                     \
    } }

#define G0_LOADA(c)                                  \
  { a0 = *(const float4*)(Ap + (c) * 64);            \
    a1 = *(const float4*)(Ap + (c) * 64 + 32); }

#define G0_STOREA(buf)                                                  \
  { uint2 p0, p1;                                                       \
    p0.x = pk2(a0.x, a0.y); p0.y = pk2(a0.z, a0.w);                     \
    p1.x = pk2(a1.x, a1.y); p1.y = pk2(a1.z, a1.w);                     \
    *(uint2*)&Asb[buf][aw0] = p0;                                       \
    *(uint2*)&Asb[buf][aw1] = p1; }

#define G0_COMPUTE(buf)                                                 \
  { const int arow = mt * 16 + lrow;                                    \
    const int aswz = (arow & 7) << 4;                                   \
    _Pragma("unroll")                                                   \
    for (int kk = 0; kk < 2; kk++) {                                    \
      short8 af = *(const short8*)&Asb[buf][(arow * 128 + ((quad * 16 + kk * 64) ^ aswz)) >> 1]; \
      _Pragma("unroll")                                                 \
      for (int nt = 0; nt < 4; nt++) {                                  \
        const int brow = (nh + nt) * 16 + lrow;                         \
        short8 bfr = *(const short8*)&Bsb[buf][(brow * 128 + ((quad * 16 + kk * 64) ^ ((brow & 7) << 4))) >> 1]; \
        acc[nt] = __builtin_amdgcn_mfma_f32_16x16x32_bf16(af, bfr, acc[nt], 0, 0, 0); \
      }                                                                 \
    } }

  float4e acc[4];
#pragma unroll
  for (int i = 0; i < 4; i++) { acc[i][0]=0.f; acc[i][1]=0.f; acc[i][2]=0.f; acc[i][3]=0.f; }

  // prologue: stage step 0 (B direct-to-LDS, A via regs)
  G0_LOADB(0, 0);
  G0_LOADA(0);
  G0_STOREA(0);
  __syncthreads();   // drains B loads too (vmcnt(0) before s_barrier)

#pragma unroll
  for (int c = 0; c < 8; c++) {
    if (c < 7) {
      G0_LOADB((c + 1) & 1, c + 1);   // fire-and-forget into next buffer
      G0_LOADA(c + 1);
      __builtin_amdgcn_sched_barrier(0);   // pin issues before compute
    }
    G0_COMPUTE(c & 1);
    if (c < 7) G0_STOREA((c + 1) & 1);
    __syncthreads();
  }

#pragma unroll
  for (int nt = 0; nt < 4; nt++) {
    const int col = (nh + nt) * 16 + lrow;
#pragma unroll
    for (int r = 0; r < 4; r++) {
      const int row = m0 + mt * 16 + quad * 4 + r;
      if (row < NN)
        xp[(size_t)ks * (NN * D1) + (size_t)row * D1 + col] = acc[nt][r];
    }
  }
}

// xb = bf16(xp0+xp1+xp2+xp3)
__global__ void reduce_kernel(const float* __restrict__ xp,
                              unsigned short* __restrict__ xb) {
  int idx = (blockIdx.x * 256 + threadIdx.x) * 4;
  if (idx >= NN * D1) return;
  float4 a = *(const float4*)&xp[idx];
  float4 b = *(const float4*)&xp[NN * D1 + idx];
  float4 c = *(const float4*)&xp[2 * NN * D1 + idx];
  float4 d = *(const float4*)&xp[3 * NN * D1 + idx];
  ushort4 o;
  o.x = f2bf(a.x + b.x + c.x + d.x); o.y = f2bf(a.y + b.y + c.y + d.y);
  o.z = f2bf(a.z + b.z + c.z + d.z); o.w = f2bf(a.w + b.w + c.w + d.w);
  *(ushort4*)&xb[idx] = o;
}

// ---------------------------------------------------------------------------
// agg1e: A1b[n, b*128+i] = bf16( sum_{e->n} esc_e*comp1[r_e,b]*x[src_e,i] )
// ---------------------------------------------------------------------------
__global__ __launch_bounds__(256) void agg1e_kernel(
    const unsigned short* __restrict__ xb, const int* __restrict__ cur,
    const int* __restrict__ rec, const float* __restrict__ esc,
    const float* __restrict__ comp, unsigned short* __restrict__ A1b) {
  __shared__ float s_comp[RR * 8];
  const int tid = threadIdx.x;
  for (int i = tid; i < RR * 8; i += 256) s_comp[i] = comp[i];
  __syncthreads();
  const int wv = tid >> 6, lane = tid & 63;
  const int n = blockIdx.x * 4 + wv;
  if (n >= NN) return;
  float acc[8][2];
#pragma unroll
  for (int b = 0; b < 8; b++) { acc[b][0] = 0.f; acc[b][1] = 0.f; }
  int cnt = cur[n]; if (cnt > MAXD) cnt = MAXD;
  const int beg = n * MAXD, end = beg + cnt;
  int idx = beg;
  for (; idx + 3 < end; idx += 4) {
    int rc[4]; float sc[4]; unsigned int xv[4];
#pragma unroll
    for (int u = 0; u < 4; u++) {
      rc[u] = rec[idx + u];
      sc[u] = esc[idx + u];
    }
#pragma unroll
    for (int u = 0; u < 4; u++)
      xv[u] = *(const unsigned int*)&xb[(size_t)(rc[u] & 16383) * D1 + lane * 2];
#pragma unroll
    for (int u = 0; u < 4; u++) {
      const float* cb = &s_comp[(rc[u] >> 14) * 8];
      float x0 = __uint_as_float((xv[u] & 0xffffu) << 16);
      float x1 = __uint_as_float(xv[u] & 0xffff0000u);
#pragma unroll
      for (int b = 0; b < 8; b++) {
        float w = sc[u] * cb[b];
        acc[b][0] += w * x0;
        acc[b][1] += w * x1;
      }
    }
  }
  for (; idx < end; idx++) {
    int rc = rec[idx];
    float sc = esc[idx];
    unsigned int xv = *(const unsigned int*)&xb[(size_t)(rc & 16383) * D1 + lane * 2];
    const float* cb = &s_comp[(rc >> 14) * 8];
    float x0 = __uint_as_float((xv & 0xffffu) << 16);
    float x1 = __uint_as_float(xv & 0xffff0000u);
#pragma unroll
    for (int b = 0; b < 8; b++) {
      float w = sc * cb[b];
      acc[b][0] += w * x0;
      acc[b][1] += w * x1;
    }
  }
#pragma unroll
  for (int b = 0; b < 8; b++) {
    ushort2 o; o.x = f2bf(acc[b][0]); o.y = f2bf(acc[b][1]);
    *(ushort2*)&A1b[(size_t)n * 1024 + b * 128 + lane * 2] = o;
  }
}

// ---------------------------------------------------------------------------
// agg2e: A2b[n, b*64+i] = bf16( sum_{e->n} esc_e*comp2[r_e,b]*h[src_e,i] )
// ---------------------------------------------------------------------------
__global__ __launch_bounds__(256) void agg2e_kernel(
    const unsigned short* __restrict__ hb, const int* __restrict__ cur,
    const int* __restrict__ rec, const float* __restrict__ esc,
    const float* __restrict__ comp, unsigned short* __restrict__ A2b) {
  __shared__ float s_comp[RR * 8];
  const int tid = threadIdx.x;
  for (int i = tid; i < RR * 8; i += 256) s_comp[i] = comp[i];
  __syncthreads();
  const int wv = tid >> 6, lane = tid & 63;
  const int n = blockIdx.x * 4 + wv;
  if (n >= NN) return;
  float acc[8];
#pragma unroll
  for (int b = 0; b < 8; b++) acc[b] = 0.f;
  int cnt = cur[n]; if (cnt > MAXD) cnt = MAXD;
  const int beg = n * MAXD, end = beg + cnt;
  int idx = beg;
  for (; idx + 3 < end; idx += 4) {
    int rc[4]; float sc[4]; float hv[4];
#pragma unroll
    for (int u = 0; u < 4; u++) {
      rc[u] = rec[idx + u];
      sc[u] = esc[idx + u];
    }
#pragma unroll
    for (int u = 0; u < 4; u++)
      hv[u] = bf2f(hb[(size_t)(rc[u] & 16383) * D2 + lane]);
#pragma unroll
    for (int u = 0; u < 4; u++) {
      const float* cb = &s_comp[(rc[u] >> 14) * 8];
#pragma unroll
      for (int b = 0; b < 8; b++) acc[b] += sc[u] * cb[b] * hv[u];
    }
  }
  for (; idx < end; idx++) {
    int rc = rec[idx];
    float sc = esc[idx];
    float hv = bf2f(hb[(size_t)(rc & 16383) * D2 + lane]);
    const float* cb = &s_comp[(rc >> 14) * 8];
#pragma unroll
    for (int b = 0; b < 8; b++) acc[b] += sc * cb[b] * hv;
  }
#pragma unroll
  for (int b = 0; b < 8; b++)
    A2b[(size_t)n * 512 + b * 64 + lane] = f2bf(acc[b]);
}

// ---------------------------------------------------------------------------
// hlayer: hb = bf16(relu([xb|A1b](K=1152) @ Wc1T + bias1))
// tile M=32 x N=64, BK=64, 18 K-steps, ONE barrier per step, pinned prefetch.
// ---------------------------------------------------------------------------
__global__ __launch_bounds__(256) void hlayer_mfma(
    const unsigned short* __restrict__ xb, const unsigned short* __restrict__ A1b,
    const unsigned short* __restrict__ Wt, const float* __restrict__ bias1,
    unsigned short* __restrict__ hb) {
  __shared__ __align__(16) unsigned short Asb[2][32 * 64];   // 8 KB
  __shared__ __align__(16) unsigned short Bsb[2][64 * 64];   // 16 KB
  const int tid = threadIdx.x;
  const int m0 = blockIdx.x * 32;
  const int wv = tid >> 6, lane = tid & 63;
  const int lrow = lane & 15, quad = lane >> 4;
  const int mt = wv >> 1, nb = wv & 1;    // wave: 16 rows x 32 cols

  const int ar = tid >> 3, ac = tid & 7;
  int gr = m0 + ar; if (gr >= NN) gr = NN - 1;
  const unsigned short* Ax = &xb[(size_t)gr * D1 + ac * 8];     // steps 0-1
  const unsigned short* Aa = &A1b[(size_t)gr * 1024 + ac * 8];  // steps 2-17
  const int asw = (ar & 7) << 4;
  const int aw = (ar * 128 + ((ac * 16) ^ asw)) >> 1;

  const int br = tid >> 2, bq = tid & 3;
  const unsigned short* Bp = &Wt[(size_t)br * 1152 + bq * 16];
  const int bsw = (br & 7) << 4;
  const int bw0 = (br * 128 + ((bq * 32) ^ bsw)) >> 1;
  const int bw1 = (br * 128 + ((bq * 32 + 16) ^ bsw)) >> 1;

  uint4 ra, rb0, rb1;

#define H_LOADG(c)                                                       \
  { int kb = (c) * 64;                                                   \
    ra  = (kb < 128) ? *(const uint4*)(Ax + kb)                          \
                     : *(const uint4*)(Aa + (kb - 128));                 \
    rb0 = *(const uint4*)(Bp + kb);                                      \
    rb1 = *(const uint4*)(Bp + kb + 8); }

#define H_STOREL(buf)                                                    \
  { *(uint4*)&Asb[buf][aw]  = ra;                                        \
    *(uint4*)&Bsb[buf][bw0] = rb0;                                       \
    *(uint4*)&Bsb[buf][bw1] = rb1; }

#define H_COMPUTE(buf)                                                   \
  { const int arow = mt * 16 + lrow;                                     \
    const int aswz = (arow & 7) << 4;                                    \
    _Pragma("unroll")                                                    \
    for (int kk = 0; kk < 2; kk++) {                                     \
      short8 af = *(const short8*)&Asb[buf][(arow * 128 + ((quad * 16 + kk * 64) ^ aswz)) >> 1]; \
      _Pragma("unroll")                                                  \
      for (int nt = 0; nt < 2; nt++) {                                   \
        const int brow = nb * 32 + nt * 16 + lrow;                       \
        short8 bfr = *(const short8*)&Bsb[buf][(brow * 128 + ((quad * 16 + kk * 64) ^ ((brow & 7) << 4))) >> 1]; \
        acc[nt] = __builtin_amdgcn_mfma_f32_16x16x32_bf16(af, bfr, acc[nt], 0, 0, 0); \
      }                                                                  \
    } }

  float4e acc[2];
#pragma unroll
  for (int i = 0; i < 2; i++) { acc[i][0]=0.f; acc[i][1]=0.f; acc[i][2]=0.f; acc[i][3]=0.f; }

  H_LOADG(0);
  H_STOREL(0);
  __syncthreads();

#pragma unroll
  for (int c = 0; c < 18; c++) {
    if (c < 17) {
      H_LOADG(c + 1);
      __builtin_amdgcn_sched_barrier(0);   // pin prefetch before compute
    }
    H_COMPUTE(c & 1);
    if (c < 17) H_STOREL((c + 1) & 1);
    __syncthreads();
  }

#pragma unroll
  for (int nt = 0; nt < 2; nt++) {
    int col = nb * 32 + nt * 16 + lrow;
    float bv = bias1[col];
#pragma unroll
    for (int r = 0; r < 4; r++) {
      int row = m0 + mt * 16 + quad * 4 + r;
      if (row < NN)
        hb[(size_t)row * D2 + col] = f2bf(fmaxf(acc[nt][r] + bv, 0.f));
    }
  }
}

// ---------------------------------------------------------------------------
// out: out = [hb|A2b](K=576) @ Wc2T + bias2
// tile M=32 x N=32, BK=64, 9 K-steps, ONE barrier per step, pinned prefetch.
// ---------------------------------------------------------------------------
__global__ __launch_bounds__(256) void out_mfma(
    const unsigned short* __restrict__ hb, const unsigned short* __restrict__ A2b,
    const unsigned short* __restrict__ Wt, const float* __restrict__ bias2,
    float* __restrict__ out) {
  __shared__ __align__(16) unsigned short Asb[2][32 * 64];   // 8 KB
  __shared__ __align__(16) unsigned short Bsb[2][32 * 64];   // 8 KB
  const int tid = threadIdx.x;
  const int m0 = blockIdx.x * 32;
  const int wv = tid >> 6, lane = tid & 63;
  const int lrow = lane & 15, quad = lane >> 4;
  const int mt = wv >> 1, ntn = wv & 1;   // wave: 16 rows x 16 cols

  const int ar = tid >> 3, ac = tid & 7;
  int gr = m0 + ar; if (gr >= NN) gr = NN - 1;
  const unsigned short* Ah = &hb[(size_t)gr * D2 + ac * 8];     // step 0
  const unsigned short* Aa = &A2b[(size_t)gr * 512 + ac * 8];   // steps 1-8
  const unsigned short* Bp = &Wt[(size_t)ar * 576 + ac * 8];
  const int asw = (ar & 7) << 4;
  const int aw = (ar * 128 + ((ac * 16) ^ asw)) >> 1;

  uint4 ra, rb;

#define O_LOADG(c)                                                       \
  { int kb = (c) * 64;                                                   \
    ra = (kb < 64) ? *(const uint4*)(Ah)                                 \
                   : *(const uint4*)(Aa + (kb - 64));                    \
    rb = *(const uint4*)(Bp + kb); }

#define O_STOREL(buf)                                                    \
  { *(uint4*)&Asb[buf][aw] = ra;                                         \
    *(uint4*)&Bsb[buf][aw] = rb; }

#define O_COMPUTE(buf)                                                   \
  { const int arow = mt * 16 + lrow;                                     \
    const int aswz = (arow & 7) << 4;                                    \
    const int brow = ntn * 16 + lrow;                                    \
    const int bswz = (brow & 7) << 4;                                    \
    _Pragma("unroll")                                                    \
    for (int kk = 0; kk < 2; kk++) {                                     \
      short8 af = *(const short8*)&Asb[buf][(arow * 128 + ((quad * 16 + kk * 64) ^ aswz)) >> 1]; \
      short8 bfr = *(const short8*)&Bsb[buf][(brow * 128 + ((quad * 16 + kk * 64) ^ bswz)) >> 1]; \
      acc = __builtin_amdgcn_mfma_f32_16x16x32_bf16(af, bfr, acc, 0, 0, 0); \
    } }

  float4e acc;
  acc[0]=0.f; acc[1]=0.f; acc[2]=0.f; acc[3]=0.f;

  O_LOADG(0);
  O_STOREL(0);
  __syncthreads();

#pragma unroll
  for (int c = 0; c < 9; c++) {
    if (c < 8) {
      O_LOADG(c + 1);
      __builtin_amdgcn_sched_barrier(0);   // pin prefetch before compute
    }
    O_COMPUTE(c & 1);
    if (c < 8) O_STOREL((c + 1) & 1);
    __syncthreads();
  }

  int col = ntn * 16 + lrow;
  if (col < D3) {
    float bv = bias2[col];
#pragma unroll
    for (int r = 0; r < 4; r++) {
      int row = m0 + mt * 16 + quad * 4 + r;
      if (row < NN)
        out[(size_t)row * D3 + col] = acc[r] + bv;
    }
  }
}

// ---------------------------------------------------------------------------
extern "C" void kernel_launch(void* const* d_in, const int* in_sizes, int n_in,
                              void* d_out, int out_size, void* d_ws,
                              size_t ws_size, hipStream_t stream) {
  const float* x_drug = (const float*)d_in[0];
  const float* drug_w = (const float*)d_in[1];
  const int*   ei     = (const int*)d_in[2];
  const float* basis1 = (const float*)d_in[3];
  const float* comp1  = (const float*)d_in[4];
  const float* root1  = (const float*)d_in[5];
  const float* bias1  = (const float*)d_in[6];
  const float* basis2 = (const float*)d_in[7];
  const float* comp2  = (const float*)d_in[8];
  const float* root2  = (const float*)d_in[9];
  const float* bias2  = (const float*)d_in[10];
  float* out = (float*)d_out;

  float* ws = (float*)d_ws;
  int*   deg  = (int*)ws;                          // 1,000,000
  int*   cur  = deg + 1000000;                     // 10,016
  int*   rec  = cur + 10016;                       // 1,280,000 (NN*MAXD)
  float* esc  = (float*)(rec + NN * MAXD);         // 1,280,000
  unsigned short* xb   = (unsigned short*)(esc + NN * MAXD);       // 640,000 f
  unsigned short* hb   = (unsigned short*)((float*)xb + 640000);   // 320,000 f
  unsigned short* Btw  = (unsigned short*)((float*)hb + 320000);   // 131,072 f
  unsigned short* Wc1T = (unsigned short*)((float*)Btw + 131072);  // 36,864 f
  unsigned short* Wc2T = (unsigned short*)((float*)Wc1T + 36864);  // 9,216 f
  float* R1 = (float*)Wc2T + 9216;                 // 5,120,000 floats shared
  float* xp = R1;                                  // 4 x 1,280,000 fp32 partials
  unsigned short* A1b = (unsigned short*)R1;       // aliases xp (after reduce)
  unsigned short* A2b = (unsigned short*)R1;       // aliases A1b (after hlayer)

  // fused prep: zero deg/cur + all weight transposes (one dispatch)
  prep_kernel<<<ZBLK + CURB + WTBLK + W1BLK + W2BLK, 256, 0, stream>>>(
      drug_w, root1, basis1, root2, basis2, (int4*)deg, (int4*)cur,
      Btw, Wc1T, Wc2T);

  // CSR build: fixed-stride slots, no cnt/scan
  deg_kernel<<<(NE + 255) / 256, 256, 0, stream>>>(ei, deg);
  scatter_kernel<<<(NE + 255) / 256, 256, 0, stream>>>(ei, deg, cur, rec, esc);

  // x = x_drug @ drug_w (bf16 MFMA, K-split 4 + reduce)
  gemm0_mfma<<<dim3(313, 4), 256, 0, stream>>>(x_drug, Btw, xp);
  reduce_kernel<<<(NN * D1 / 4 + 255) / 256, 256, 0, stream>>>(xp, xb);

  // layer 1
  agg1e_kernel<<<(NN + 3) / 4, 256, 0, stream>>>(xb, cur, rec, esc, comp1, A1b);
  hlayer_mfma<<<(NN + 31) / 32, 256, 0, stream>>>(xb, A1b, Wc1T, bias1, hb);

  // layer 2
  agg2e_kernel<<<(NN + 3) / 4, 256, 0, stream>>>(hb, cur, rec, esc, comp2, A2b);
  out_mfma<<<(NN + 31) / 32, 256, 0, stream>>>(hb, A2b, Wc2T, bias2, out);
}

// Round 9
// 171.968 us; speedup vs baseline: 1.1334x; 1.0152x over previous
//
#include <hip/hip_runtime.h>

#define NN 10000    // nodes
#define RR 100      // relations
#define EE 5000     // edges per relation
#define D0 2048
#define D1 128
#define D2 64
#define D3 20
#define NE (RR*EE)  // 500000 edges total
#define MAXD 128    // fixed CSR stride per node (true max deg ~80, 11 sigma)

using short8  = __attribute__((ext_vector_type(8))) short;
using float4e = __attribute__((ext_vector_type(4))) float;

typedef const __attribute__((address_space(1))) void g_void;
typedef __attribute__((address_space(3))) void l_void;

__device__ __forceinline__ unsigned short f2bf(float f) {
  unsigned int u = __float_as_uint(f);
  unsigned int r = u + 0x7fffu + ((u >> 16) & 1u);   // RNE
  return (unsigned short)(r >> 16);
}
__device__ __forceinline__ float bf2f(unsigned short u) {
  return __uint_as_float(((unsigned int)u) << 16);
}
__device__ __forceinline__ unsigned int pk2(float lo, float hi) {
  return ((unsigned int)f2bf(hi) << 16) | (unsigned int)f2bf(lo);
}

// ---------------------------------------------------------------------------
// prep: fused {zero deg, zero cur, wtrans, wc1t, wc2t} in one dispatch
// ---------------------------------------------------------------------------
#define ZBLK 977            // 250,000 int4 zeros (deg)
#define CURB 10             // 2,504 int4 zeros (cur)
#define WTBLK 1024          // 262,144 elems
#define W1BLK 288           // 73,728 elems
#define W2BLK 72            // 18,432 elems
__global__ __launch_bounds__(256) void prep_kernel(
    const float* __restrict__ W, const float* __restrict__ root1,
    const float* __restrict__ basis1, const float* __restrict__ root2,
    const float* __restrict__ basis2, int4* __restrict__ deg4,
    int4* __restrict__ cur4,
    unsigned short* __restrict__ Btw, unsigned short* __restrict__ Wc1T,
    unsigned short* __restrict__ Wc2T) {
  const int b = blockIdx.x, tid = threadIdx.x;
  if (b < ZBLK) {
    int i = b * 256 + tid;
    if (i < (NN * RR) / 4) deg4[i] = make_int4(0, 0, 0, 0);
  } else if (b < ZBLK + CURB) {
    int i = (b - ZBLK) * 256 + tid;
    if (i < 2504) cur4[i] = make_int4(0, 0, 0, 0);
  } else if (b < ZBLK + CURB + WTBLK) {
    int idx = (b - ZBLK - CURB) * 256 + tid;                 // 128*2048, exact
    int n = idx >> 11, k = idx & 2047;
    Btw[idx] = f2bf(W[(size_t)k * 128 + n]);
  } else if (b < ZBLK + CURB + WTBLK + W1BLK) {
    int idx = (b - ZBLK - CURB - WTBLK) * 256 + tid;         // 64*1152, exact
    int o = idx / 1152, j = idx - o * 1152;
    float v = (j < 128) ? root1[j * 64 + o] : basis1[(j - 128) * 64 + o];
    Wc1T[idx] = f2bf(v);
  } else {
    int idx = (b - ZBLK - CURB - WTBLK - W1BLK) * 256 + tid; // 32*576, exact
    int c = idx / 576, j = idx - c * 576;
    float v = 0.f;
    if (c < 20) v = (j < 64) ? root2[j * 20 + c] : basis2[(j - 64) * 20 + c];
    Wc2T[idx] = f2bf(v);
  }
}

// ---------------------------------------------------------------------------
// CSR build — fixed-stride (MAXD per node): no cnt/scan kernels needed.
// ---------------------------------------------------------------------------
__global__ void deg_kernel(const int* __restrict__ ei, int* __restrict__ deg) {
  int gid = blockIdx.x * 256 + threadIdx.x;
  if (gid >= NE) return;
  int r = gid / EE, e = gid - r * EE;
  int d = ei[r * 2 * EE + EE + e];
  atomicAdd(&deg[r * NN + d], 1);
}

// rec = (r<<14)|src, esc = 1/max(deg,1); slot = atomic bump of cur[d]
__global__ void scatter_kernel(const int* __restrict__ ei,
                               const int* __restrict__ deg,
                               int* __restrict__ cur, int* __restrict__ rec,
                               float* __restrict__ esc) {
  int gid = blockIdx.x * 256 + threadIdx.x;
  if (gid >= NE) return;
  int r = gid / EE, e = gid - r * EE;
  int s = ei[r * 2 * EE + e];
  int d = ei[r * 2 * EE + EE + e];
  int p = atomicAdd(&cur[d], 1);
  if (p < MAXD) {
    rec[d * MAXD + p] = (r << 14) | s;
    esc[d * MAXD + p] = 1.0f / fmaxf((float)deg[r * NN + d], 1.0f);
  }
}

// ---------------------------------------------------------------------------
// gemm0 v2 — NO split-K: xb = bf16(x_drug @ drug_w) directly.
// Tile M=16, N=128, K=2048, BK=64 (32 steps). Grid = 625 blocks, 36KB LDS ->
// 4 blocks/CU: ALL 625 resident from t=0 (1024 slots), zero tail rounds
// (was 1252 blocks = 4.89 rounds). Eliminates xp (41MB traffic) + the
// reduce dispatch. B via global_load_lds w=16 (pre-swizzled source, m173);
// A via reg path (fp32->bf16 pack). Full-K fp32 MFMA accumulation.
// ---------------------------------------------------------------------------
__global__ __launch_bounds__(256) void gemm0_mfma(
    const float* __restrict__ A, const unsigned short* __restrict__ Btw,
    unsigned short* __restrict__ xb) {
  __shared__ __align__(16) unsigned short Asb[2][16 * 64];    // 2 x 2 KB
  __shared__ __align__(16) unsigned short Bsb[2][128 * 64];   // 2 x 16 KB
  const int tid = threadIdx.x;
  const int m0 = blockIdx.x * 16;
  const int wv = tid >> 6, lane = tid & 63;
  const int lrow = lane & 15, quad = lane >> 4;

  // A staging (reg path): row ar = tid>>4 (16 rows), piece ag = tid&15.
  // Thread loads float4 at K-offset ag*4 (row = 16 thr x 16B = 256B coalesced),
  // packs 4 bf16 (8B), stores at XOR-swizzled slot.
  const int ar = tid >> 4, ag = tid & 15;
  const float* Ap = &A[(size_t)(m0 + ar) * D0 + ag * 4];
  const int aw = (ar * 128 + ((ag * 8) ^ ((ar & 7) << 4))) >> 1;  // ushort idx

  // B staging (global_load_lds): wave w, issue i, lane l ->
  //   LDS row w*32+i*8+(l>>3), chunk l&7 ; global chunk (l&7)^(l>>3)
  const int rowB = wv * 32 + (lane >> 3);
  const int gch  = (lane & 7) ^ (lane >> 3);
  const unsigned short* BgBase = &Btw[(size_t)rowB * D0 + gch * 8];
  const int ldsB = wv * 2048;   // ushort idx of this wave's 4KB region

  float4 a0;

#define G0_LOADB(buf, c)                                                     \
  { _Pragma("unroll")                                                        \
    for (int i = 0; i < 4; i++) {                                            \
      __builtin_amdgcn_global_load_lds(                                      \
          (g_void*)(BgBase + (size_t)i * 8 * D0 + (c) * 64),                 \
          (l_void*)&Bsb[buf][ldsB + i * 512], 16, 0, 0);                     \
    } }

#define G0_LOADA(c)  { a0 = *(const float4*)(Ap + (c) * 64); }

#define G0_STOREA(buf)                                                  \
  { uint2 p0;                                                           \
    p0.x = pk2(a0.x, a0.y); p0.y = pk2(a0.z, a0.w);                     \
    *(uint2*)&Asb[buf][aw] = p0; }

#define G0_COMPUTE(buf)                                                 \
  { const int aswz = (lrow & 7) << 4;                                   \
    _Pragma("unroll")                                                   \
    for (int kk = 0; kk < 2; kk++) {                                    \
      short8 af = *(const short8*)&Asb[buf][(lrow * 128 + ((quad * 16 + kk * 64) ^ aswz)) >> 1]; \
      _Pragma("unroll")                                                 \
      for (int nt = 0; nt < 2; nt++) {                                  \
        const int brow = wv * 32 + nt * 16 + lrow;                      \
        short8 bfr = *(const short8*)&Bsb[buf][(brow * 128 + ((quad * 16 + kk * 64) ^ ((brow & 7) << 4))) >> 1]; \
        acc[nt] = __builtin_amdgcn_mfma_f32_16x16x32_bf16(af, bfr, acc[nt], 0, 0, 0); \
      }                                                                 \
    } }

  float4e acc[2];
#pragma unroll
  for (int i = 0; i < 2; i++) { acc[i][0]=0.f; acc[i][1]=0.f; acc[i][2]=0.f; acc[i][3]=0.f; }

  // prologue: stage step 0
  G0_LOADB(0, 0);
  G0_LOADA(0);
  G0_STOREA(0);
  __syncthreads();   // drains B loads (vmcnt(0) before s_barrier)

#pragma unroll 4
  for (int c = 0; c < 32; c++) {
    if (c < 31) {
      G0_LOADB((c + 1) & 1, c + 1);   // fire-and-forget into next buffer
      G0_LOADA(c + 1);
      __builtin_amdgcn_sched_barrier(0);   // pin issues before compute
    }
    G0_COMPUTE(c & 1);
    if (c < 31) G0_STOREA((c + 1) & 1);
    __syncthreads();
  }

  // epilogue: write bf16 xb directly (no split-K partials, no reduce pass)
#pragma unroll
  for (int nt = 0; nt < 2; nt++) {
    const int col = wv * 32 + nt * 16 + lrow;
#pragma unroll
    for (int r = 0; r < 4; r++) {
      const int row = m0 + quad * 4 + r;
      xb[(size_t)row * D1 + col] = f2bf(acc[nt][r]);
    }
  }
}

// ---------------------------------------------------------------------------
// agg1e: A1b[n, b*128+i] = bf16( sum_{e->n} esc_e*comp1[r_e,b]*x[src_e,i] )
// ---------------------------------------------------------------------------
__global__ __launch_bounds__(256) void agg1e_kernel(
    const unsigned short* __restrict__ xb, const int* __restrict__ cur,
    const int* __restrict__ rec, const float* __restrict__ esc,
    const float* __restrict__ comp, unsigned short* __restrict__ A1b) {
  __shared__ float s_comp[RR * 8];
  const int tid = threadIdx.x;
  for (int i = tid; i < RR * 8; i += 256) s_comp[i] = comp[i];
  __syncthreads();
  const int wv = tid >> 6, lane = tid & 63;
  const int n = blockIdx.x * 4 + wv;
  if (n >= NN) return;
  float acc[8][2];
#pragma unroll
  for (int b = 0; b < 8; b++) { acc[b][0] = 0.f; acc[b][1] = 0.f; }
  int cnt = cur[n]; if (cnt > MAXD) cnt = MAXD;
  const int beg = n * MAXD, end = beg + cnt;
  int idx = beg;
  for (; idx + 3 < end; idx += 4) {
    int rc[4]; float sc[4]; unsigned int xv[4];
#pragma unroll
    for (int u = 0; u < 4; u++) {
      rc[u] = rec[idx + u];
      sc[u] = esc[idx + u];
    }
#pragma unroll
    for (int u = 0; u < 4; u++)
      xv[u] = *(const unsigned int*)&xb[(size_t)(rc[u] & 16383) * D1 + lane * 2];
#pragma unroll
    for (int u = 0; u < 4; u++) {
      const float* cb = &s_comp[(rc[u] >> 14) * 8];
      float x0 = __uint_as_float((xv[u] & 0xffffu) << 16);
      float x1 = __uint_as_float(xv[u] & 0xffff0000u);
#pragma unroll
      for (int b = 0; b < 8; b++) {
        float w = sc[u] * cb[b];
        acc[b][0] += w * x0;
        acc[b][1] += w * x1;
      }
    }
  }
  for (; idx < end; idx++) {
    int rc = rec[idx];
    float sc = esc[idx];
    unsigned int xv = *(const unsigned int*)&xb[(size_t)(rc & 16383) * D1 + lane * 2];
    const float* cb = &s_comp[(rc >> 14) * 8];
    float x0 = __uint_as_float((xv & 0xffffu) << 16);
    float x1 = __uint_as_float(xv & 0xffff0000u);
#pragma unroll
    for (int b = 0; b < 8; b++) {
      float w = sc * cb[b];
      acc[b][0] += w * x0;
      acc[b][1] += w * x1;
    }
  }
#pragma unroll
  for (int b = 0; b < 8; b++) {
    ushort2 o; o.x = f2bf(acc[b][0]); o.y = f2bf(acc[b][1]);
    *(ushort2*)&A1b[(size_t)n * 1024 + b * 128 + lane * 2] = o;
  }
}

// ---------------------------------------------------------------------------
// agg2e: A2b[n, b*64+i] = bf16( sum_{e->n} esc_e*comp2[r_e,b]*h[src_e,i] )
// ---------------------------------------------------------------------------
__global__ __launch_bounds__(256) void agg2e_kernel(
    const unsigned short* __restrict__ hb, const int* __restrict__ cur,
    const int* __restrict__ rec, const float* __restrict__ esc,
    const float* __restrict__ comp, unsigned short* __restrict__ A2b) {
  __shared__ float s_comp[RR * 8];
  const int tid = threadIdx.x;
  for (int i = tid; i < RR * 8; i += 256) s_comp[i] = comp[i];
  __syncthreads();
  const int wv = tid >> 6, lane = tid & 63;
  const int n = blockIdx.x * 4 + wv;
  if (n >= NN) return;
  float acc[8];
#pragma unroll
  for (int b = 0; b < 8; b++) acc[b] = 0.f;
  int cnt = cur[n]; if (cnt > MAXD) cnt = MAXD;
  const int beg = n * MAXD, end = beg + cnt;
  int idx = beg;
  for (; idx + 3 < end; idx += 4) {
    int rc[4]; float sc[4]; float hv[4];
#pragma unroll
    for (int u = 0; u < 4; u++) {
      rc[u] = rec[idx + u];
      sc[u] = esc[idx + u];
    }
#pragma unroll
    for (int u = 0; u < 4; u++)
      hv[u] = bf2f(hb[(size_t)(rc[u] & 16383) * D2 + lane]);
#pragma unroll
    for (int u = 0; u < 4; u++) {
      const float* cb = &s_comp[(rc[u] >> 14) * 8];
#pragma unroll
      for (int b = 0; b < 8; b++) acc[b] += sc[u] * cb[b] * hv[u];
    }
  }
  for (; idx < end; idx++) {
    int rc = rec[idx];
    float sc = esc[idx];
    float hv = bf2f(hb[(size_t)(rc & 16383) * D2 + lane]);
    const float* cb = &s_comp[(rc >> 14) * 8];
#pragma unroll
    for (int b = 0; b < 8; b++) acc[b] += sc * cb[b] * hv;
  }
#pragma unroll
  for (int b = 0; b < 8; b++)
    A2b[(size_t)n * 512 + b * 64 + lane] = f2bf(acc[b]);
}

// ---------------------------------------------------------------------------
// hlayer: hb = bf16(relu([xb|A1b](K=1152) @ Wc1T + bias1))
// tile M=32 x N=64, BK=64, 18 K-steps, ONE barrier per step, pinned prefetch.
// ---------------------------------------------------------------------------
__global__ __launch_bounds__(256) void hlayer_mfma(
    const unsigned short* __restrict__ xb, const unsigned short* __restrict__ A1b,
    const unsigned short* __restrict__ Wt, const float* __restrict__ bias1,
    unsigned short* __restrict__ hb) {
  __shared__ __align__(16) unsigned short Asb[2][32 * 64];   // 8 KB
  __shared__ __align__(16) unsigned short Bsb[2][64 * 64];   // 16 KB
  const int tid = threadIdx.x;
  const int m0 = blockIdx.x * 32;
  const int wv = tid >> 6, lane = tid & 63;
  const int lrow = lane & 15, quad = lane >> 4;
  const int mt = wv >> 1, nb = wv & 1;    // wave: 16 rows x 32 cols

  const int ar = tid >> 3, ac = tid & 7;
  int gr = m0 + ar; if (gr >= NN) gr = NN - 1;
  const unsigned short* Ax = &xb[(size_t)gr * D1 + ac * 8];     // steps 0-1
  const unsigned short* Aa = &A1b[(size_t)gr * 1024 + ac * 8];  // steps 2-17
  const int asw = (ar & 7) << 4;
  const int aw = (ar * 128 + ((ac * 16) ^ asw)) >> 1;

  const int br = tid >> 2, bq = tid & 3;
  const unsigned short* Bp = &Wt[(size_t)br * 1152 + bq * 16];
  const int bsw = (br & 7) << 4;
  const int bw0 = (br * 128 + ((bq * 32) ^ bsw)) >> 1;
  const int bw1 = (br * 128 + ((bq * 32 + 16) ^ bsw)) >> 1;

  uint4 ra, rb0, rb1;

#define H_LOADG(c)                                                       \
  { int kb = (c) * 64;                                                   \
    ra  = (kb < 128) ? *(const uint4*)(Ax + kb)                          \
                     : *(const uint4*)(Aa + (kb - 128));                 \
    rb0 = *(const uint4*)(Bp + kb);                                      \
    rb1 = *(const uint4*)(Bp + kb + 8); }

#define H_STOREL(buf)                                                    \
  { *(uint4*)&Asb[buf][aw]  = ra;                                        \
    *(uint4*)&Bsb[buf][bw0] = rb0;                                       \
    *(uint4*)&Bsb[buf][bw1] = rb1; }

#define H_COMPUTE(buf)                                                   \
  { const int arow = mt * 16 + lrow;                                     \
    const int aswz = (arow & 7) << 4;                                    \
    _Pragma("unroll")                                                    \
    for (int kk = 0; kk < 2; kk++) {                                     \
      short8 af = *(const short8*)&Asb[buf][(arow * 128 + ((quad * 16 + kk * 64) ^ aswz)) >> 1]; \
      _Pragma("unroll")                                                  \
      for (int nt = 0; nt < 2; nt++) {                                   \
        const int brow = nb * 32 + nt * 16 + lrow;                       \
        short8 bfr = *(const short8*)&Bsb[buf][(brow * 128 + ((quad * 16 + kk * 64) ^ ((brow & 7) << 4))) >> 1]; \
        acc[nt] = __builtin_amdgcn_mfma_f32_16x16x32_bf16(af, bfr, acc[nt], 0, 0, 0); \
      }                                                                  \
    } }

  float4e acc[2];
#pragma unroll
  for (int i = 0; i < 2; i++) { acc[i][0]=0.f; acc[i][1]=0.f; acc[i][2]=0.f; acc[i][3]=0.f; }

  H_LOADG(0);
  H_STOREL(0);
  __syncthreads();

#pragma unroll
  for (int c = 0; c < 18; c++) {
    if (c < 17) {
      H_LOADG(c + 1);
      __builtin_amdgcn_sched_barrier(0);   // pin prefetch before compute
    }
    H_COMPUTE(c & 1);
    if (c < 17) H_STOREL((c + 1) & 1);
    __syncthreads();
  }

#pragma unroll
  for (int nt = 0; nt < 2; nt++) {
    int col = nb * 32 + nt * 16 + lrow;
    float bv = bias1[col];
#pragma unroll
    for (int r = 0; r < 4; r++) {
      int row = m0 + mt * 16 + quad * 4 + r;
      if (row < NN)
        hb[(size_t)row * D2 + col] = f2bf(fmaxf(acc[nt][r] + bv, 0.f));
    }
  }
}

// ---------------------------------------------------------------------------
// out: out = [hb|A2b](K=576) @ Wc2T + bias2
// tile M=32 x N=32, BK=64, 9 K-steps, ONE barrier per step, pinned prefetch.
// ---------------------------------------------------------------------------
__global__ __launch_bounds__(256) void out_mfma(
    const unsigned short* __restrict__ hb, const unsigned short* __restrict__ A2b,
    const unsigned short* __restrict__ Wt, const float* __restrict__ bias2,
    float* __restrict__ out) {
  __shared__ __align__(16) unsigned short Asb[2][32 * 64];   // 8 KB
  __shared__ __align__(16) unsigned short Bsb[2][32 * 64];   // 8 KB
  const int tid = threadIdx.x;
  const int m0 = blockIdx.x * 32;
  const int wv = tid >> 6, lane = tid & 63;
  const int lrow = lane & 15, quad = lane >> 4;
  const int mt = wv >> 1, ntn = wv & 1;   // wave: 16 rows x 16 cols

  const int ar = tid >> 3, ac = tid & 7;
  int gr = m0 + ar; if (gr >= NN) gr = NN - 1;
  const unsigned short* Ah = &hb[(size_t)gr * D2 + ac * 8];     // step 0
  const unsigned short* Aa = &A2b[(size_t)gr * 512 + ac * 8];   // steps 1-8
  const unsigned short* Bp = &Wt[(size_t)ar * 576 + ac * 8];
  const int asw = (ar & 7) << 4;
  const int aw = (ar * 128 + ((ac * 16) ^ asw)) >> 1;

  uint4 ra, rb;

#define O_LOADG(c)                                                       \
  { int kb = (c) * 64;                                                   \
    ra = (kb < 64) ? *(const uint4*)(Ah)                                 \
                   : *(const uint4*)(Aa + (kb - 64));                    \
    rb = *(const uint4*)(Bp + kb); }

#define O_STOREL(buf)                                                    \
  { *(uint4*)&Asb[buf][aw] = ra;                                         \
    *(uint4*)&Bsb[buf][aw] = rb; }

#define O_COMPUTE(buf)                                                   \
  { const int arow = mt * 16 + lrow;                                     \
    const int aswz = (arow & 7) << 4;                                    \
    const int brow = ntn * 16 + lrow;                                    \
    const int bswz = (brow & 7) << 4;                                    \
    _Pragma("unroll")                                                    \
    for (int kk = 0; kk < 2; kk++) {                                     \
      short8 af = *(const short8*)&Asb[buf][(arow * 128 + ((quad * 16 + kk * 64) ^ aswz)) >> 1]; \
      short8 bfr = *(const short8*)&Bsb[buf][(brow * 128 + ((quad * 16 + kk * 64) ^ bswz)) >> 1]; \
      acc = __builtin_amdgcn_mfma_f32_16x16x32_bf16(af, bfr, acc, 0, 0, 0); \
    } }

  float4e acc;
  acc[0]=0.f; acc[1]=0.f; acc[2]=0.f; acc[3]=0.f;

  O_LOADG(0);
  O_STOREL(0);
  __syncthreads();

#pragma unroll
  for (int c = 0; c < 9; c++) {
    if (c < 8) {
      O_LOADG(c + 1);
      __builtin_amdgcn_sched_barrier(0);   // pin prefetch before compute
    }
    O_COMPUTE(c & 1);
    if (c < 8) O_STOREL((c + 1) & 1);
    __syncthreads();
  }

  int col = ntn * 16 + lrow;
  if (col < D3) {
    float bv = bias2[col];
#pragma unroll
    for (int r = 0; r < 4; r++) {
      int row = m0 + mt * 16 + quad * 4 + r;
      if (row < NN)
        out[(size_t)row * D3 + col] = acc[r] + bv;
    }
  }
}

// ---------------------------------------------------------------------------
extern "C" void kernel_launch(void* const* d_in, const int* in_sizes, int n_in,
                              void* d_out, int out_size, void* d_ws,
                              size_t ws_size, hipStream_t stream) {
  const float* x_drug = (const float*)d_in[0];
  const float* drug_w = (const float*)d_in[1];
  const int*   ei     = (const int*)d_in[2];
  const float* basis1 = (const float*)d_in[3];
  const float* comp1  = (const float*)d_in[4];
  const float* root1  = (const float*)d_in[5];
  const float* bias1  = (const float*)d_in[6];
  const float* basis2 = (const float*)d_in[7];
  const float* comp2  = (const float*)d_in[8];
  const float* root2  = (const float*)d_in[9];
  const float* bias2  = (const float*)d_in[10];
  float* out = (float*)d_out;

  float* ws = (float*)d_ws;
  int*   deg  = (int*)ws;                          // 1,000,000
  int*   cur  = deg + 1000000;                     // 10,016
  int*   rec  = cur + 10016;                       // 1,280,000 (NN*MAXD)
  float* esc  = (float*)(rec + NN * MAXD);         // 1,280,000
  unsigned short* xb   = (unsigned short*)(esc + NN * MAXD);       // 640,000 f
  unsigned short* hb   = (unsigned short*)((float*)xb + 640000);   // 320,000 f
  unsigned short* Btw  = (unsigned short*)((float*)hb + 320000);   // 131,072 f
  unsigned short* Wc1T = (unsigned short*)((float*)Btw + 131072);  // 36,864 f
  unsigned short* Wc2T = (unsigned short*)((float*)Wc1T + 36864);  // 9,216 f
  float* R1 = (float*)Wc2T + 9216;                 // shared scratch region
  unsigned short* A1b = (unsigned short*)R1;       // 10.24M ushort (20.5MB)
  unsigned short* A2b = (unsigned short*)R1;       // aliases A1b (after hlayer)

  // fused prep: zero deg/cur + all weight transposes (one dispatch)
  prep_kernel<<<ZBLK + CURB + WTBLK + W1BLK + W2BLK, 256, 0, stream>>>(
      drug_w, root1, basis1, root2, basis2, (int4*)deg, (int4*)cur,
      Btw, Wc1T, Wc2T);

  // CSR build: fixed-stride slots, no cnt/scan
  deg_kernel<<<(NE + 255) / 256, 256, 0, stream>>>(ei, deg);
  scatter_kernel<<<(NE + 255) / 256, 256, 0, stream>>>(ei, deg, cur, rec, esc);

  // x = bf16(x_drug @ drug_w) — single-pass, no split-K, no reduce
  gemm0_mfma<<<NN / 16, 256, 0, stream>>>(x_drug, Btw, xb);

  // layer 1
  agg1e_kernel<<<(NN + 3) / 4, 256, 0, stream>>>(xb, cur, rec, esc, comp1, A1b);
  hlayer_mfma<<<(NN + 31) / 32, 256, 0, stream>>>(xb, A1b, Wc1T, bias1, hb);

  // layer 2
  agg2e_kernel<<<(NN + 3) / 4, 256, 0, stream>>>(hb, cur, rec, esc, comp2, A2b);
  out_mfma<<<(NN + 31) / 32, 256, 0, stream>>>(hb, A2b, Wc2T, bias2, out);
}

// Round 10
// 151.965 us; speedup vs baseline: 1.2826x; 1.1316x over previous
//
#include <hip/hip_runtime.h>

#define NN 10000    // nodes
#define RR 100      // relations
#define EE 5000     // edges per relation
#define D0 2048
#define D1 128
#define D2 64
#define D3 20
#define NE (RR*EE)  // 500000 edges total
#define MAXD 128    // fixed CSR stride per node (true max total deg ~80)

using short8  = __attribute__((ext_vector_type(8))) short;
using float4e = __attribute__((ext_vector_type(4))) float;

typedef const __attribute__((address_space(1))) void g_void;
typedef __attribute__((address_space(3))) void l_void;

__device__ __forceinline__ unsigned short f2bf(float f) {
  unsigned int u = __float_as_uint(f);
  unsigned int r = u + 0x7fffu + ((u >> 16) & 1u);   // RNE
  return (unsigned short)(r >> 16);
}
__device__ __forceinline__ float bf2f(unsigned short u) {
  return __uint_as_float(((unsigned int)u) << 16);
}
__device__ __forceinline__ unsigned int pk2(float lo, float hi) {
  return ((unsigned int)f2bf(hi) << 16) | (unsigned int)f2bf(lo);
}

// ---------------------------------------------------------------------------
// prep: fused {zero cur, wtrans, wc1t, wc2t} in one dispatch.
// (deg array deleted entirely -> no 4MB zero, no deg_kernel.)
// ---------------------------------------------------------------------------
#define CURB 10             // 2,504 int4 zeros (cur)
#define WTBLK 1024          // 262,144 elems
#define W1BLK 288           // 73,728 elems
#define W2BLK 72            // 18,432 elems
__global__ __launch_bounds__(256) void prep_kernel(
    const float* __restrict__ W, const float* __restrict__ root1,
    const float* __restrict__ basis1, const float* __restrict__ root2,
    const float* __restrict__ basis2, int4* __restrict__ cur4,
    unsigned short* __restrict__ Btw, unsigned short* __restrict__ Wc1T,
    unsigned short* __restrict__ Wc2T) {
  const int b = blockIdx.x, tid = threadIdx.x;
  if (b < CURB) {
    int i = b * 256 + tid;
    if (i < 2504) cur4[i] = make_int4(0, 0, 0, 0);
  } else if (b < CURB + WTBLK) {
    int idx = (b - CURB) * 256 + tid;                 // 128*2048, exact
    int n = idx >> 11, k = idx & 2047;
    Btw[idx] = f2bf(W[(size_t)k * 128 + n]);
  } else if (b < CURB + WTBLK + W1BLK) {
    int idx = (b - CURB - WTBLK) * 256 + tid;         // 64*1152, exact
    int o = idx / 1152, j = idx - o * 1152;
    float v = (j < 128) ? root1[j * 64 + o] : basis1[(j - 128) * 64 + o];
    Wc1T[idx] = f2bf(v);
  } else {
    int idx = (b - CURB - WTBLK - W1BLK) * 256 + tid; // 32*576, exact
    int c = idx / 576, j = idx - c * 576;
    float v = 0.f;
    if (c < 20) v = (j < 64) ? root2[j * 20 + c] : basis2[(j - 64) * 20 + c];
    Wc2T[idx] = f2bf(v);
  }
}

// ---------------------------------------------------------------------------
// scatter: ONE random 4B store per edge (rec only; esc moved to finalize).
// Round-9 counters: old scatter moved 65MB of line-amplified traffic
// (rec+esc+deg random) at 1.38 TB/s = 47.5us. This halves the random lines.
// ---------------------------------------------------------------------------
__global__ void scatter_kernel(const int* __restrict__ ei,
                               int* __restrict__ cur, int* __restrict__ rec) {
  int gid = blockIdx.x * 256 + threadIdx.x;
  if (gid >= NE) return;
  int r = gid / EE, e = gid - r * EE;
  int s = ei[r * 2 * EE + e];
  int d = ei[r * 2 * EE + EE + e];
  int p = atomicAdd(&cur[d], 1);
  if (p < MAXD) rec[d * MAXD + p] = (r << 14) | s;
}

// ---------------------------------------------------------------------------
// finalize: esc[n*MAXD+i] = 1/deg(r_i, n) via per-node relation histogram.
// deg(r,n) = #edges into n with relation r == count of r among node n's
// slots (identical semantics to the old deg array). One wave per node:
// coalesced rec read, LDS histogram, coalesced esc write. ~4MB total, ~2us.
// Grid = NN/4 = 2500 exact (no divergent barrier).
// ---------------------------------------------------------------------------
__global__ __launch_bounds__(256) void finalize_kernel(
    const int* __restrict__ cur, const int* __restrict__ rec,
    float* __restrict__ esc) {
  __shared__ int hist[4][RR];
  const int tid = threadIdx.x;
  const int wv = tid >> 6, lane = tid & 63;
  const int n = blockIdx.x * 4 + wv;
  for (int i = lane; i < RR; i += 64) hist[wv][i] = 0;
  __syncthreads();
  int cnt = cur[n]; if (cnt > MAXD) cnt = MAXD;
  int r0 = 0, r1 = 0;
  if (lane < cnt) {
    r0 = rec[n * MAXD + lane] >> 14;
    atomicAdd(&hist[wv][r0], 1);
  }
  if (lane + 64 < cnt) {
    r1 = rec[n * MAXD + lane + 64] >> 14;
    atomicAdd(&hist[wv][r1], 1);
  }
  __syncthreads();
  if (lane < cnt)      esc[n * MAXD + lane]      = 1.0f / (float)hist[wv][r0];
  if (lane + 64 < cnt) esc[n * MAXD + lane + 64] = 1.0f / (float)hist[wv][r1];
}

// ---------------------------------------------------------------------------
// gemm0 — NO split-K: xb = bf16(x_drug @ drug_w) directly.
// Tile M=16, N=128, K=2048, BK=64 (32 steps). 625 blocks, 36KB LDS, 4/CU.
// B via global_load_lds w=16 (pre-swizzled source); A via reg path.
// ---------------------------------------------------------------------------
__global__ __launch_bounds__(256) void gemm0_mfma(
    const float* __restrict__ A, const unsigned short* __restrict__ Btw,
    unsigned short* __restrict__ xb) {
  __shared__ __align__(16) unsigned short Asb[2][16 * 64];    // 2 x 2 KB
  __shared__ __align__(16) unsigned short Bsb[2][128 * 64];   // 2 x 16 KB
  const int tid = threadIdx.x;
  const int m0 = blockIdx.x * 16;
  const int wv = tid >> 6, lane = tid & 63;
  const int lrow = lane & 15, quad = lane >> 4;

  const int ar = tid >> 4, ag = tid & 15;
  const float* Ap = &A[(size_t)(m0 + ar) * D0 + ag * 4];
  const int aw = (ar * 128 + ((ag * 8) ^ ((ar & 7) << 4))) >> 1;  // ushort idx

  const int rowB = wv * 32 + (lane >> 3);
  const int gch  = (lane & 7) ^ (lane >> 3);
  const unsigned short* BgBase = &Btw[(size_t)rowB * D0 + gch * 8];
  const int ldsB = wv * 2048;   // ushort idx of this wave's 4KB region

  float4 a0;

#define G0_LOADB(buf, c)                                                     \
  { _Pragma("unroll")                                                        \
    for (int i = 0; i < 4; i++) {                                            \
      __builtin_amdgcn_global_load_lds(                                      \
          (g_void*)(BgBase + (size_t)i * 8 * D0 + (c) * 64),                 \
          (l_void*)&Bsb[buf][ldsB + i * 512], 16, 0, 0);                     \
    } }

#define G0_LOADA(c)  { a0 = *(const float4*)(Ap + (c) * 64); }

#define G0_STOREA(buf)                                                  \
  { uint2 p0;                                                           \
    p0.x = pk2(a0.x, a0.y); p0.y = pk2(a0.z, a0.w);                     \
    *(uint2*)&Asb[buf][aw] = p0; }

#define G0_COMPUTE(buf)                                                 \
  { const int aswz = (lrow & 7) << 4;                                   \
    _Pragma("unroll")                                                   \
    for (int kk = 0; kk < 2; kk++) {                                    \
      short8 af = *(const short8*)&Asb[buf][(lrow * 128 + ((quad * 16 + kk * 64) ^ aswz)) >> 1]; \
      _Pragma("unroll")                                                 \
      for (int nt = 0; nt < 2; nt++) {                                  \
        const int brow = wv * 32 + nt * 16 + lrow;                      \
        short8 bfr = *(const short8*)&Bsb[buf][(brow * 128 + ((quad * 16 + kk * 64) ^ ((brow & 7) << 4))) >> 1]; \
        acc[nt] = __builtin_amdgcn_mfma_f32_16x16x32_bf16(af, bfr, acc[nt], 0, 0, 0); \
      }                                                                 \
    } }

  float4e acc[2];
#pragma unroll
  for (int i = 0; i < 2; i++) { acc[i][0]=0.f; acc[i][1]=0.f; acc[i][2]=0.f; acc[i][3]=0.f; }

  G0_LOADB(0, 0);
  G0_LOADA(0);
  G0_STOREA(0);
  __syncthreads();

#pragma unroll 4
  for (int c = 0; c < 32; c++) {
    if (c < 31) {
      G0_LOADB((c + 1) & 1, c + 1);
      G0_LOADA(c + 1);
      __builtin_amdgcn_sched_barrier(0);
    }
    G0_COMPUTE(c & 1);
    if (c < 31) G0_STOREA((c + 1) & 1);
    __syncthreads();
  }

#pragma unroll
  for (int nt = 0; nt < 2; nt++) {
    const int col = wv * 32 + nt * 16 + lrow;
#pragma unroll
    for (int r = 0; r < 4; r++) {
      const int row = m0 + quad * 4 + r;
      xb[(size_t)row * D1 + col] = f2bf(acc[nt][r]);
    }
  }
}

// ---------------------------------------------------------------------------
// agg1e: A1b[n, b*128+i] = bf16( sum_{e->n} esc_e*comp1[r_e,b]*x[src_e,i] )
// ---------------------------------------------------------------------------
__global__ __launch_bounds__(256) void agg1e_kernel(
    const unsigned short* __restrict__ xb, const int* __restrict__ cur,
    const int* __restrict__ rec, const float* __restrict__ esc,
    const float* __restrict__ comp, unsigned short* __restrict__ A1b) {
  __shared__ float s_comp[RR * 8];
  const int tid = threadIdx.x;
  for (int i = tid; i < RR * 8; i += 256) s_comp[i] = comp[i];
  __syncthreads();
  const int wv = tid >> 6, lane = tid & 63;
  const int n = blockIdx.x * 4 + wv;
  if (n >= NN) return;
  float acc[8][2];
#pragma unroll
  for (int b = 0; b < 8; b++) { acc[b][0] = 0.f; acc[b][1] = 0.f; }
  int cnt = cur[n]; if (cnt > MAXD) cnt = MAXD;
  const int beg = n * MAXD, end = beg + cnt;
  int idx = beg;
  for (; idx + 3 < end; idx += 4) {
    int rc[4]; float sc[4]; unsigned int xv[4];
#pragma unroll
    for (int u = 0; u < 4; u++) {
      rc[u] = rec[idx + u];
      sc[u] = esc[idx + u];
    }
#pragma unroll
    for (int u = 0; u < 4; u++)
      xv[u] = *(const unsigned int*)&xb[(size_t)(rc[u] & 16383) * D1 + lane * 2];
#pragma unroll
    for (int u = 0; u < 4; u++) {
      const float* cb = &s_comp[(rc[u] >> 14) * 8];
      float x0 = __uint_as_float((xv[u] & 0xffffu) << 16);
      float x1 = __uint_as_float(xv[u] & 0xffff0000u);
#pragma unroll
      for (int b = 0; b < 8; b++) {
        float w = sc[u] * cb[b];
        acc[b][0] += w * x0;
        acc[b][1] += w * x1;
      }
    }
  }
  for (; idx < end; idx++) {
    int rc = rec[idx];
    float sc = esc[idx];
    unsigned int xv = *(const unsigned int*)&xb[(size_t)(rc & 16383) * D1 + lane * 2];
    const float* cb = &s_comp[(rc >> 14) * 8];
    float x0 = __uint_as_float((xv & 0xffffu) << 16);
    float x1 = __uint_as_float(xv & 0xffff0000u);
#pragma unroll
    for (int b = 0; b < 8; b++) {
      float w = sc * cb[b];
      acc[b][0] += w * x0;
      acc[b][1] += w * x1;
    }
  }
#pragma unroll
  for (int b = 0; b < 8; b++) {
    ushort2 o; o.x = f2bf(acc[b][0]); o.y = f2bf(acc[b][1]);
    *(ushort2*)&A1b[(size_t)n * 1024 + b * 128 + lane * 2] = o;
  }
}

// ---------------------------------------------------------------------------
// agg2e: A2b[n, b*64+i] = bf16( sum_{e->n} esc_e*comp2[r_e,b]*h[src_e,i] )
// ---------------------------------------------------------------------------
__global__ __launch_bounds__(256) void agg2e_kernel(
    const unsigned short* __restrict__ hb, const int* __restrict__ cur,
    const int* __restrict__ rec, const float* __restrict__ esc,
    const float* __restrict__ comp, unsigned short* __restrict__ A2b) {
  __shared__ float s_comp[RR * 8];
  const int tid = threadIdx.x;
  for (int i = tid; i < RR * 8; i += 256) s_comp[i] = comp[i];
  __syncthreads();
  const int wv = tid >> 6, lane = tid & 63;
  const int n = blockIdx.x * 4 + wv;
  if (n >= NN) return;
  float acc[8];
#pragma unroll
  for (int b = 0; b < 8; b++) acc[b] = 0.f;
  int cnt = cur[n]; if (cnt > MAXD) cnt = MAXD;
  const int beg = n * MAXD, end = beg + cnt;
  int idx = beg;
  for (; idx + 3 < end; idx += 4) {
    int rc[4]; float sc[4]; float hv[4];
#pragma unroll
    for (int u = 0; u < 4; u++) {
      rc[u] = rec[idx + u];
      sc[u] = esc[idx + u];
    }
#pragma unroll
    for (int u = 0; u < 4; u++)
      hv[u] = bf2f(hb[(size_t)(rc[u] & 16383) * D2 + lane]);
#pragma unroll
    for (int u = 0; u < 4; u++) {
      const float* cb = &s_comp[(rc[u] >> 14) * 8];
#pragma unroll
      for (int b = 0; b < 8; b++) acc[b] += sc[u] * cb[b] * hv[u];
    }
  }
  for (; idx < end; idx++) {
    int rc = rec[idx];
    float sc = esc[idx];
    float hv = bf2f(hb[(size_t)(rc & 16383) * D2 + lane]);
    const float* cb = &s_comp[(rc >> 14) * 8];
#pragma unroll
    for (int b = 0; b < 8; b++) acc[b] += sc * cb[b] * hv;
  }
#pragma unroll
  for (int b = 0; b < 8; b++)
    A2b[(size_t)n * 512 + b * 64 + lane] = f2bf(acc[b]);
}

// ---------------------------------------------------------------------------
// hlayer: hb = bf16(relu([xb|A1b](K=1152) @ Wc1T + bias1))
// tile M=32 x N=64, BK=64, 18 K-steps, ONE barrier per step, pinned prefetch.
// ---------------------------------------------------------------------------
__global__ __launch_bounds__(256) void hlayer_mfma(
    const unsigned short* __restrict__ xb, const unsigned short* __restrict__ A1b,
    const unsigned short* __restrict__ Wt, const float* __restrict__ bias1,
    unsigned short* __restrict__ hb) {
  __shared__ __align__(16) unsigned short Asb[2][32 * 64];   // 8 KB
  __shared__ __align__(16) unsigned short Bsb[2][64 * 64];   // 16 KB
  const int tid = threadIdx.x;
  const int m0 = blockIdx.x * 32;
  const int wv = tid >> 6, lane = tid & 63;
  const int lrow = lane & 15, quad = lane >> 4;
  const int mt = wv >> 1, nb = wv & 1;    // wave: 16 rows x 32 cols

  const int ar = tid >> 3, ac = tid & 7;
  int gr = m0 + ar; if (gr >= NN) gr = NN - 1;
  const unsigned short* Ax = &xb[(size_t)gr * D1 + ac * 8];     // steps 0-1
  const unsigned short* Aa = &A1b[(size_t)gr * 1024 + ac * 8];  // steps 2-17
  const int asw = (ar & 7) << 4;
  const int aw = (ar * 128 + ((ac * 16) ^ asw)) >> 1;

  const int br = tid >> 2, bq = tid & 3;
  const unsigned short* Bp = &Wt[(size_t)br * 1152 + bq * 16];
  const int bsw = (br & 7) << 4;
  const int bw0 = (br * 128 + ((bq * 32) ^ bsw)) >> 1;
  const int bw1 = (br * 128 + ((bq * 32 + 16) ^ bsw)) >> 1;

  uint4 ra, rb0, rb1;

#define H_LOADG(c)                                                       \
  { int kb = (c) * 64;                                                   \
    ra  = (kb < 128) ? *(const uint4*)(Ax + kb)                          \
                     : *(const uint4*)(Aa + (kb - 128));                 \
    rb0 = *(const uint4*)(Bp + kb);                                      \
    rb1 = *(const uint4*)(Bp + kb + 8); }

#define H_STOREL(buf)                                                    \
  { *(uint4*)&Asb[buf][aw]  = ra;                                        \
    *(uint4*)&Bsb[buf][bw0] = rb0;                                       \
    *(uint4*)&Bsb[buf][bw1] = rb1; }

#define H_COMPUTE(buf)                                                   \
  { const int arow = mt * 16 + lrow;                                     \
    const int aswz = (arow & 7) << 4;                                    \
    _Pragma("unroll")                                                    \
    for (int kk = 0; kk < 2; kk++) {                                     \
      short8 af = *(const short8*)&Asb[buf][(arow * 128 + ((quad * 16 + kk * 64) ^ aswz)) >> 1]; \
      _Pragma("unroll")                                                  \
      for (int nt = 0; nt < 2; nt++) {                                   \
        const int brow = nb * 32 + nt * 16 + lrow;                       \
        short8 bfr = *(const short8*)&Bsb[buf][(brow * 128 + ((quad * 16 + kk * 64) ^ ((brow & 7) << 4))) >> 1]; \
        acc[nt] = __builtin_amdgcn_mfma_f32_16x16x32_bf16(af, bfr, acc[nt], 0, 0, 0); \
      }                                                                  \
    } }

  float4e acc[2];
#pragma unroll
  for (int i = 0; i < 2; i++) { acc[i][0]=0.f; acc[i][1]=0.f; acc[i][2]=0.f; acc[i][3]=0.f; }

  H_LOADG(0);
  H_STOREL(0);
  __syncthreads();

#pragma unroll
  for (int c = 0; c < 18; c++) {
    if (c < 17) {
      H_LOADG(c + 1);
      __builtin_amdgcn_sched_barrier(0);   // pin prefetch before compute
    }
    H_COMPUTE(c & 1);
    if (c < 17) H_STOREL((c + 1) & 1);
    __syncthreads();
  }

#pragma unroll
  for (int nt = 0; nt < 2; nt++) {
    int col = nb * 32 + nt * 16 + lrow;
    float bv = bias1[col];
#pragma unroll
    for (int r = 0; r < 4; r++) {
      int row = m0 + mt * 16 + quad * 4 + r;
      if (row < NN)
        hb[(size_t)row * D2 + col] = f2bf(fmaxf(acc[nt][r] + bv, 0.f));
    }
  }
}

// ---------------------------------------------------------------------------
// out: out = [hb|A2b](K=576) @ Wc2T + bias2
// tile M=32 x N=32, BK=64, 9 K-steps, ONE barrier per step, pinned prefetch.
// ---------------------------------------------------------------------------
__global__ __launch_bounds__(256) void out_mfma(
    const unsigned short* __restrict__ hb, const unsigned short* __restrict__ A2b,
    const unsigned short* __restrict__ Wt, const float* __restrict__ bias2,
    float* __restrict__ out) {
  __shared__ __align__(16) unsigned short Asb[2][32 * 64];   // 8 KB
  __shared__ __align__(16) unsigned short Bsb[2][32 * 64];   // 8 KB
  const int tid = threadIdx.x;
  const int m0 = blockIdx.x * 32;
  const int wv = tid >> 6, lane = tid & 63;
  const int lrow = lane & 15, quad = lane >> 4;
  const int mt = wv >> 1, ntn = wv & 1;   // wave: 16 rows x 16 cols

  const int ar = tid >> 3, ac = tid & 7;
  int gr = m0 + ar; if (gr >= NN) gr = NN - 1;
  const unsigned short* Ah = &hb[(size_t)gr * D2 + ac * 8];     // step 0
  const unsigned short* Aa = &A2b[(size_t)gr * 512 + ac * 8];   // steps 1-8
  const unsigned short* Bp = &Wt[(size_t)ar * 576 + ac * 8];
  const int asw = (ar & 7) << 4;
  const int aw = (ar * 128 + ((ac * 16) ^ asw)) >> 1;

  uint4 ra, rb;

#define O_LOADG(c)                                                       \
  { int kb = (c) * 64;                                                   \
    ra = (kb < 64) ? *(const uint4*)(Ah)                                 \
                   : *(const uint4*)(Aa + (kb - 64));                    \
    rb = *(const uint4*)(Bp + kb); }

#define O_STOREL(buf)                                                    \
  { *(uint4*)&Asb[buf][aw] = ra;                                         \
    *(uint4*)&Bsb[buf][aw] = rb; }

#define O_COMPUTE(buf)                                                   \
  { const int arow = mt * 16 + lrow;                                     \
    const int aswz = (arow & 7) << 4;                                    \
    const int brow = ntn * 16 + lrow;                                    \
    const int bswz = (brow & 7) << 4;                                    \
    _Pragma("unroll")                                                    \
    for (int kk = 0; kk < 2; kk++) {                                     \
      short8 af = *(const short8*)&Asb[buf][(arow * 128 + ((quad * 16 + kk * 64) ^ aswz)) >> 1]; \
      short8 bfr = *(const short8*)&Bsb[buf][(brow * 128 + ((quad * 16 + kk * 64) ^ bswz)) >> 1]; \
      acc = __builtin_amdgcn_mfma_f32_16x16x32_bf16(af, bfr, acc, 0, 0, 0); \
    } }

  float4e acc;
  acc[0]=0.f; acc[1]=0.f; acc[2]=0.f; acc[3]=0.f;

  O_LOADG(0);
  O_STOREL(0);
  __syncthreads();

#pragma unroll
  for (int c = 0; c < 9; c++) {
    if (c < 8) {
      O_LOADG(c + 1);
      __builtin_amdgcn_sched_barrier(0);   // pin prefetch before compute
    }
    O_COMPUTE(c & 1);
    if (c < 8) O_STOREL((c + 1) & 1);
    __syncthreads();
  }

  int col = ntn * 16 + lrow;
  if (col < D3) {
    float bv = bias2[col];
#pragma unroll
    for (int r = 0; r < 4; r++) {
      int row = m0 + mt * 16 + quad * 4 + r;
      if (row < NN)
        out[(size_t)row * D3 + col] = acc[r] + bv;
    }
  }
}

// ---------------------------------------------------------------------------
extern "C" void kernel_launch(void* const* d_in, const int* in_sizes, int n_in,
                              void* d_out, int out_size, void* d_ws,
                              size_t ws_size, hipStream_t stream) {
  const float* x_drug = (const float*)d_in[0];
  const float* drug_w = (const float*)d_in[1];
  const int*   ei     = (const int*)d_in[2];
  const float* basis1 = (const float*)d_in[3];
  const float* comp1  = (const float*)d_in[4];
  const float* root1  = (const float*)d_in[5];
  const float* bias1  = (const float*)d_in[6];
  const float* basis2 = (const float*)d_in[7];
  const float* comp2  = (const float*)d_in[8];
  const float* root2  = (const float*)d_in[9];
  const float* bias2  = (const float*)d_in[10];
  float* out = (float*)d_out;

  float* ws = (float*)d_ws;
  int*   cur  = (int*)ws;                          // 10,016
  int*   rec  = cur + 10016;                       // 1,280,000 (NN*MAXD)
  float* esc  = (float*)(rec + NN * MAXD);         // 1,280,000
  unsigned short* xb   = (unsigned short*)(esc + NN * MAXD);       // 640,000 f
  unsigned short* hb   = (unsigned short*)((float*)xb + 640000);   // 320,000 f
  unsigned short* Btw  = (unsigned short*)((float*)hb + 320000);   // 131,072 f
  unsigned short* Wc1T = (unsigned short*)((float*)Btw + 131072);  // 36,864 f
  unsigned short* Wc2T = (unsigned short*)((float*)Wc1T + 36864);  // 9,216 f
  float* R1 = (float*)Wc2T + 9216;                 // shared scratch region
  unsigned short* A1b = (unsigned short*)R1;       // 10.24M ushort (20.5MB)
  unsigned short* A2b = (unsigned short*)R1;       // aliases A1b (after hlayer)

  // fused prep: zero cur + all weight transposes (one dispatch)
  prep_kernel<<<CURB + WTBLK + W1BLK + W2BLK, 256, 0, stream>>>(
      drug_w, root1, basis1, root2, basis2, (int4*)cur, Btw, Wc1T, Wc2T);

  // CSR build: scatter rec (single random 4B store/edge), then esc via
  // per-node histogram (all coalesced). deg array/kernel deleted.
  scatter_kernel<<<(NE + 255) / 256, 256, 0, stream>>>(ei, cur, rec);
  finalize_kernel<<<NN / 4, 256, 0, stream>>>(cur, rec, esc);

  // x = bf16(x_drug @ drug_w) — single-pass, no split-K, no reduce
  gemm0_mfma<<<NN / 16, 256, 0, stream>>>(x_drug, Btw, xb);

  // layer 1
  agg1e_kernel<<<(NN + 3) / 4, 256, 0, stream>>>(xb, cur, rec, esc, comp1, A1b);
  hlayer_mfma<<<(NN + 31) / 32, 256, 0, stream>>>(xb, A1b, Wc1T, bias1, hb);

  // layer 2
  agg2e_kernel<<<(NN + 3) / 4, 256, 0, stream>>>(hb, cur, rec, esc, comp2, A2b);
  out_mfma<<<(NN + 31) / 32, 256, 0, stream>>>(hb, A2b, Wc2T, bias2, out);
}

// Round 11
// 147.563 us; speedup vs baseline: 1.3209x; 1.0298x over previous
//
#include <hip/hip_runtime.h>

#define NN 10000    // nodes
#define RR 100      // relations
#define EE 5000     // edges per relation
#define D0 2048
#define D1 128
#define D2 64
#define D3 20
#define NE (RR*EE)  // 500000 edges total
#define MAXD 128    // fixed CSR stride per node (true max total deg ~80)

using short8  = __attribute__((ext_vector_type(8))) short;
using float4e = __attribute__((ext_vector_type(4))) float;

typedef const __attribute__((address_space(1))) void g_void;
typedef __attribute__((address_space(3))) void l_void;

__device__ __forceinline__ unsigned short f2bf(float f) {
  unsigned int u = __float_as_uint(f);
  unsigned int r = u + 0x7fffu + ((u >> 16) & 1u);   // RNE
  return (unsigned short)(r >> 16);
}
__device__ __forceinline__ float bf2f(unsigned short u) {
  return __uint_as_float(((unsigned int)u) << 16);
}
__device__ __forceinline__ unsigned int pk2(float lo, float hi) {
  return ((unsigned int)f2bf(hi) << 16) | (unsigned int)f2bf(lo);
}

// ---------------------------------------------------------------------------
// prep: fused {zero cur, wtrans, wc1t, wc2t} in one dispatch.
// ---------------------------------------------------------------------------
#define CURB 10             // 2,504 int4 zeros (cur)
#define WTBLK 1024          // 262,144 elems
#define W1BLK 288           // 73,728 elems
#define W2BLK 72            // 18,432 elems
__global__ __launch_bounds__(256) void prep_kernel(
    const float* __restrict__ W, const float* __restrict__ root1,
    const float* __restrict__ basis1, const float* __restrict__ root2,
    const float* __restrict__ basis2, int4* __restrict__ cur4,
    unsigned short* __restrict__ Btw, unsigned short* __restrict__ Wc1T,
    unsigned short* __restrict__ Wc2T) {
  const int b = blockIdx.x, tid = threadIdx.x;
  if (b < CURB) {
    int i = b * 256 + tid;
    if (i < 2504) cur4[i] = make_int4(0, 0, 0, 0);
  } else if (b < CURB + WTBLK) {
    int idx = (b - CURB) * 256 + tid;                 // 128*2048, exact
    int n = idx >> 11, k = idx & 2047;
    Btw[idx] = f2bf(W[(size_t)k * 128 + n]);
  } else if (b < CURB + WTBLK + W1BLK) {
    int idx = (b - CURB - WTBLK) * 256 + tid;         // 64*1152, exact
    int o = idx / 1152, j = idx - o * 1152;
    float v = (j < 128) ? root1[j * 64 + o] : basis1[(j - 128) * 64 + o];
    Wc1T[idx] = f2bf(v);
  } else {
    int idx = (b - CURB - WTBLK - W1BLK) * 256 + tid; // 32*576, exact
    int c = idx / 576, j = idx - c * 576;
    float v = 0.f;
    if (c < 20) v = (j < 64) ? root2[j * 20 + c] : basis2[(j - 64) * 20 + c];
    Wc2T[idx] = f2bf(v);
  }
}

// ---------------------------------------------------------------------------
// scatter: ONE random 4B store per edge (rec only).
// ---------------------------------------------------------------------------
__global__ void scatter_kernel(const int* __restrict__ ei,
                               int* __restrict__ cur, int* __restrict__ rec) {
  int gid = blockIdx.x * 256 + threadIdx.x;
  if (gid >= NE) return;
  int r = gid / EE, e = gid - r * EE;
  int s = ei[r * 2 * EE + e];
  int d = ei[r * 2 * EE + EE + e];
  int p = atomicAdd(&cur[d], 1);
  if (p < MAXD) rec[d * MAXD + p] = (r << 14) | s;
}

// ---------------------------------------------------------------------------
// gemm0 — counted-vmcnt pipeline (T4): xb = bf16(x_drug @ drug_w).
// Tile M=16, N=128, K=2048, BK=64 (32 steps). 625 blocks, 52KB LDS, 3/CU
// (all resident). B: 3 LDS buffers via global_load_lds, loaded 2 steps
// ahead; A: a0/a1 register pair loaded 2 ahead, packed 1 ahead into 2-buf
// Asb. Barrier = raw `s_waitcnt vmcnt(5) lgkmcnt(0); s_barrier` — the 4
// B-loads + 1 A-load for step c+2 stay IN FLIGHT across the barrier
// (old __syncthreads drained vmcnt(0) -> 32 serial HBM round-trips/block).
// Issue order {B x4, A} makes the A-pack's auto-wait vmcnt(5), never 0.
// ---------------------------------------------------------------------------
__global__ __launch_bounds__(256, 3) void gemm0_mfma(
    const float* __restrict__ A, const unsigned short* __restrict__ Btw,
    unsigned short* __restrict__ xb) {
  __shared__ __align__(16) unsigned short Asb[2][16 * 64];    // 2 x 2 KB
  __shared__ __align__(16) unsigned short Bsb[3][128 * 64];   // 3 x 16 KB
  const int tid = threadIdx.x;
  const int m0 = blockIdx.x * 16;
  const int wv = tid >> 6, lane = tid & 63;
  const int lrow = lane & 15, quad = lane >> 4;

  // A staging: row ar = tid>>4 (16 rows), piece ag = tid&15 (float4).
  const int ar = tid >> 4, ag = tid & 15;
  const float* Ap = &A[(size_t)(m0 + ar) * D0 + ag * 4];
  const int aw = (ar * 128 + ((ag * 8) ^ ((ar & 7) << 4))) >> 1;  // ushort idx

  // B staging (global_load_lds): wave w, issue i, lane l ->
  //   LDS row w*32+i*8+(l>>3), chunk l&7 ; global chunk (l&7)^(l>>3)
  const int rowB = wv * 32 + (lane >> 3);
  const int gch  = (lane & 7) ^ (lane >> 3);
  const unsigned short* BgBase = &Btw[(size_t)rowB * D0 + gch * 8];
  const int ldsB = wv * 2048;   // ushort idx of this wave's 4KB region

  float4 a0, a1;

#define G0_LOADB(buf, c)                                                     \
  { _Pragma("unroll")                                                        \
    for (int i = 0; i < 4; i++) {                                            \
      __builtin_amdgcn_global_load_lds(                                      \
          (g_void*)(BgBase + (size_t)i * 8 * D0 + (c) * 64),                 \
          (l_void*)&Bsb[buf][ldsB + i * 512], 16, 0, 0);                     \
    } }

#define G0_LOADA(reg, c)  { reg = *(const float4*)(Ap + (c) * 64); }

#define G0_PACKA(reg, buf)                                              \
  { uint2 p0;                                                           \
    p0.x = pk2(reg.x, reg.y); p0.y = pk2(reg.z, reg.w);                 \
    *(uint2*)&Asb[buf][aw] = p0; }

#define G0_COMPUTE(abuf, bbuf)                                          \
  { const int aswz = (lrow & 7) << 4;                                   \
    _Pragma("unroll")                                                   \
    for (int kk = 0; kk < 2; kk++) {                                    \
      short8 af = *(const short8*)&Asb[abuf][(lrow * 128 + ((quad * 16 + kk * 64) ^ aswz)) >> 1]; \
      _Pragma("unroll")                                                 \
      for (int nt = 0; nt < 2; nt++) {                                  \
        const int brow = wv * 32 + nt * 16 + lrow;                      \
        short8 bfr = *(const short8*)&Bsb[bbuf][(brow * 128 + ((quad * 16 + kk * 64) ^ ((brow & 7) << 4))) >> 1]; \
        acc[nt] = __builtin_amdgcn_mfma_f32_16x16x32_bf16(af, bfr, acc[nt], 0, 0, 0); \
      }                                                                 \
    } }

  float4e acc[2];
#pragma unroll
  for (int i = 0; i < 2; i++) { acc[i][0]=0.f; acc[i][1]=0.f; acc[i][2]=0.f; acc[i][3]=0.f; }

  // prologue: data0 staged; data1 in regs; B0,B1 in flight
  G0_LOADA(a0, 0);
  G0_LOADB(0, 0);
  G0_LOADB(1, 1);
  G0_PACKA(a0, 0);            // auto-waits A(0): vmcnt(8)
  G0_LOADA(a1, 1);
  // need B(0) landed: outstanding after = B(1)x4 + A(1) = 5
  asm volatile("s_waitcnt vmcnt(5) lgkmcnt(0)\ns_barrier" ::: "memory");

#pragma unroll
  for (int c = 0; c < 32; c++) {
    if (c <= 29) {
      G0_LOADB((c + 2) % 3, c + 2);                       // 4 issues
      if ((c & 1) == 0) { G0_LOADA(a0, c + 2); }          // 1 issue (youngest)
      else              { G0_LOADA(a1, c + 2); }
      __builtin_amdgcn_sched_barrier(0);                  // pin issue order
    }
    G0_COMPUTE(c & 1, c % 3);
    if (c <= 30) {
      // pack data(c+1), loaded last step: auto-wait = vmcnt(5) (B(c+2)+A(c+2) younger)
      if (((c + 1) & 1) == 0) { G0_PACKA(a0, 0); }
      else                    { G0_PACKA(a1, 1); }
      // B(c+1) is older than A(c+1) -> already landed; keep c+2 in flight.
      asm volatile("s_waitcnt vmcnt(5) lgkmcnt(0)\ns_barrier" ::: "memory");
    }
  }

#pragma unroll
  for (int nt = 0; nt < 2; nt++) {
    const int col = wv * 32 + nt * 16 + lrow;
#pragma unroll
    for (int r = 0; r < 4; r++) {
      const int row = m0 + quad * 4 + r;
      xb[(size_t)row * D1 + col] = f2bf(acc[nt][r]);
    }
  }
}

// ---------------------------------------------------------------------------
// agg1e: A1b[n, b*128+i] = bf16( sum_{e->n} esc_e*comp1[r_e,b]*x[src_e,i] )
// esc computed IN-KERNEL via per-wave LDS relation histogram (same
// 1.0f/(float)count math as the old finalize) — esc array + dispatch gone.
// Grid NN/4 exact; no early return (block barriers safe).
// ---------------------------------------------------------------------------
__global__ __launch_bounds__(256) void agg1e_kernel(
    const unsigned short* __restrict__ xb, const int* __restrict__ cur,
    const int* __restrict__ rec, const float* __restrict__ comp,
    unsigned short* __restrict__ A1b) {
  __shared__ float s_comp[RR * 8];
  __shared__ float s_rcp[4][RR];
  const int tid = threadIdx.x;
  for (int i = tid; i < RR * 8; i += 256) s_comp[i] = comp[i];
  const int wv = tid >> 6, lane = tid & 63;
  const int n = blockIdx.x * 4 + wv;          // always < NN (grid exact)
  int* hist = (int*)&s_rcp[wv][0];
  for (int i = lane; i < RR; i += 64) hist[i] = 0;
  __syncthreads();
  int cnt = cur[n]; if (cnt > MAXD) cnt = MAXD;
  if (lane < cnt)      atomicAdd(&hist[rec[n * MAXD + lane] >> 14], 1);
  if (lane + 64 < cnt) atomicAdd(&hist[rec[n * MAXD + lane + 64] >> 14], 1);
  __syncthreads();
  for (int i = lane; i < RR; i += 64) {
    int h = hist[i];
    s_rcp[wv][i] = 1.0f / (float)h;
  }
  __syncthreads();

  float acc[8][2];
#pragma unroll
  for (int b = 0; b < 8; b++) { acc[b][0] = 0.f; acc[b][1] = 0.f; }
  const int beg = n * MAXD, end = beg + cnt;
  int idx = beg;
  for (; idx + 3 < end; idx += 4) {
    int rc[4]; float sc[4]; unsigned int xv[4];
#pragma unroll
    for (int u = 0; u < 4; u++) rc[u] = rec[idx + u];
#pragma unroll
    for (int u = 0; u < 4; u++) sc[u] = s_rcp[wv][rc[u] >> 14];
#pragma unroll
    for (int u = 0; u < 4; u++)
      xv[u] = *(const unsigned int*)&xb[(size_t)(rc[u] & 16383) * D1 + lane * 2];
#pragma unroll
    for (int u = 0; u < 4; u++) {
      const float* cb = &s_comp[(rc[u] >> 14) * 8];
      float x0 = __uint_as_float((xv[u] & 0xffffu) << 16);
      float x1 = __uint_as_float(xv[u] & 0xffff0000u);
#pragma unroll
      for (int b = 0; b < 8; b++) {
        float w = sc[u] * cb[b];
        acc[b][0] += w * x0;
        acc[b][1] += w * x1;
      }
    }
  }
  for (; idx < end; idx++) {
    int rc = rec[idx];
    float sc = s_rcp[wv][rc >> 14];
    unsigned int xv = *(const unsigned int*)&xb[(size_t)(rc & 16383) * D1 + lane * 2];
    const float* cb = &s_comp[(rc >> 14) * 8];
    float x0 = __uint_as_float((xv & 0xffffu) << 16);
    float x1 = __uint_as_float(xv & 0xffff0000u);
#pragma unroll
    for (int b = 0; b < 8; b++) {
      float w = sc * cb[b];
      acc[b][0] += w * x0;
      acc[b][1] += w * x1;
    }
  }
#pragma unroll
  for (int b = 0; b < 8; b++) {
    ushort2 o; o.x = f2bf(acc[b][0]); o.y = f2bf(acc[b][1]);
    *(ushort2*)&A1b[(size_t)n * 1024 + b * 128 + lane * 2] = o;
  }
}

// ---------------------------------------------------------------------------
// agg2e: A2b[n, b*64+i] = bf16( sum_{e->n} esc_e*comp2[r_e,b]*h[src_e,i] )
// Same in-kernel esc histogram.
// ---------------------------------------------------------------------------
__global__ __launch_bounds__(256) void agg2e_kernel(
    const unsigned short* __restrict__ hb, const int* __restrict__ cur,
    const int* __restrict__ rec, const float* __restrict__ comp,
    unsigned short* __restrict__ A2b) {
  __shared__ float s_comp[RR * 8];
  __shared__ float s_rcp[4][RR];
  const int tid = threadIdx.x;
  for (int i = tid; i < RR * 8; i += 256) s_comp[i] = comp[i];
  const int wv = tid >> 6, lane = tid & 63;
  const int n = blockIdx.x * 4 + wv;          // always < NN
  int* hist = (int*)&s_rcp[wv][0];
  for (int i = lane; i < RR; i += 64) hist[i] = 0;
  __syncthreads();
  int cnt = cur[n]; if (cnt > MAXD) cnt = MAXD;
  if (lane < cnt)      atomicAdd(&hist[rec[n * MAXD + lane] >> 14], 1);
  if (lane + 64 < cnt) atomicAdd(&hist[rec[n * MAXD + lane + 64] >> 14], 1);
  __syncthreads();
  for (int i = lane; i < RR; i += 64) {
    int h = hist[i];
    s_rcp[wv][i] = 1.0f / (float)h;
  }
  __syncthreads();

  float acc[8];
#pragma unroll
  for (int b = 0; b < 8; b++) acc[b] = 0.f;
  const int beg = n * MAXD, end = beg + cnt;
  int idx = beg;
  for (; idx + 3 < end; idx += 4) {
    int rc[4]; float sc[4]; float hv[4];
#pragma unroll
    for (int u = 0; u < 4; u++) rc[u] = rec[idx + u];
#pragma unroll
    for (int u = 0; u < 4; u++) sc[u] = s_rcp[wv][rc[u] >> 14];
#pragma unroll
    for (int u = 0; u < 4; u++)
      hv[u] = bf2f(hb[(size_t)(rc[u] & 16383) * D2 + lane]);
#pragma unroll
    for (int u = 0; u < 4; u++) {
      const float* cb = &s_comp[(rc[u] >> 14) * 8];
#pragma unroll
      for (int b = 0; b < 8; b++) acc[b] += sc[u] * cb[b] * hv[u];
    }
  }
  for (; idx < end; idx++) {
    int rc = rec[idx];
    float sc = s_rcp[wv][rc >> 14];
    float hv = bf2f(hb[(size_t)(rc & 16383) * D2 + lane]);
    const float* cb = &s_comp[(rc >> 14) * 8];
#pragma unroll
    for (int b = 0; b < 8; b++) acc[b] += sc * cb[b] * hv;
  }
#pragma unroll
  for (int b = 0; b < 8; b++)
    A2b[(size_t)n * 512 + b * 64 + lane] = f2bf(acc[b]);
}

// ---------------------------------------------------------------------------
// hlayer: hb = bf16(relu([xb|A1b](K=1152) @ Wc1T + bias1))
// tile M=32 x N=64, BK=64, 18 K-steps, ONE barrier per step, pinned prefetch.
// ---------------------------------------------------------------------------
__global__ __launch_bounds__(256) void hlayer_mfma(
    const unsigned short* __restrict__ xb, const unsigned short* __restrict__ A1b,
    const unsigned short* __restrict__ Wt, const float* __restrict__ bias1,
    unsigned short* __restrict__ hb) {
  __shared__ __align__(16) unsigned short Asb[2][32 * 64];   // 8 KB
  __shared__ __align__(16) unsigned short Bsb[2][64 * 64];   // 16 KB
  const int tid = threadIdx.x;
  const int m0 = blockIdx.x * 32;
  const int wv = tid >> 6, lane = tid & 63;
  const int lrow = lane & 15, quad = lane >> 4;
  const int mt = wv >> 1, nb = wv & 1;    // wave: 16 rows x 32 cols

  const int ar = tid >> 3, ac = tid & 7;
  int gr = m0 + ar; if (gr >= NN) gr = NN - 1;
  const unsigned short* Ax = &xb[(size_t)gr * D1 + ac * 8];     // steps 0-1
  const unsigned short* Aa = &A1b[(size_t)gr * 1024 + ac * 8];  // steps 2-17
  const int asw = (ar & 7) << 4;
  const int aw = (ar * 128 + ((ac * 16) ^ asw)) >> 1;

  const int br = tid >> 2, bq = tid & 3;
  const unsigned short* Bp = &Wt[(size_t)br * 1152 + bq * 16];
  const int bsw = (br & 7) << 4;
  const int bw0 = (br * 128 + ((bq * 32) ^ bsw)) >> 1;
  const int bw1 = (br * 128 + ((bq * 32 + 16) ^ bsw)) >> 1;

  uint4 ra, rb0, rb1;

#define H_LOADG(c)                                                       \
  { int kb = (c) * 64;                                                   \
    ra  = (kb < 128) ? *(const uint4*)(Ax + kb)                          \
                     : *(const uint4*)(Aa + (kb - 128));                 \
    rb0 = *(const uint4*)(Bp + kb);                                      \
    rb1 = *(const uint4*)(Bp + kb + 8); }

#define H_STOREL(buf)                                                    \
  { *(uint4*)&Asb[buf][aw]  = ra;                                        \
    *(uint4*)&Bsb[buf][bw0] = rb0;                                       \
    *(uint4*)&Bsb[buf][bw1] = rb1; }

#define H_COMPUTE(buf)                                                   \
  { const int arow = mt * 16 + lrow;                                     \
    const int aswz = (arow & 7) << 4;                                    \
    _Pragma("unroll")                                                    \
    for (int kk = 0; kk < 2; kk++) {                                     \
      short8 af = *(const short8*)&Asb[buf][(arow * 128 + ((quad * 16 + kk * 64) ^ aswz)) >> 1]; \
      _Pragma("unroll")                                                  \
      for (int nt = 0; nt < 2; nt++) {                                   \
        const int brow = nb * 32 + nt * 16 + lrow;                       \
        short8 bfr = *(const short8*)&Bsb[buf][(brow * 128 + ((quad * 16 + kk * 64) ^ ((brow & 7) << 4))) >> 1]; \
        acc[nt] = __builtin_amdgcn_mfma_f32_16x16x32_bf16(af, bfr, acc[nt], 0, 0, 0); \
      }                                                                  \
    } }

  float4e acc[2];
#pragma unroll
  for (int i = 0; i < 2; i++) { acc[i][0]=0.f; acc[i][1]=0.f; acc[i][2]=0.f; acc[i][3]=0.f; }

  H_LOADG(0);
  H_STOREL(0);
  __syncthreads();

#pragma unroll
  for (int c = 0; c < 18; c++) {
    if (c < 17) {
      H_LOADG(c + 1);
      __builtin_amdgcn_sched_barrier(0);   // pin prefetch before compute
    }
    H_COMPUTE(c & 1);
    if (c < 17) H_STOREL((c + 1) & 1);
    __syncthreads();
  }

#pragma unroll
  for (int nt = 0; nt < 2; nt++) {
    int col = nb * 32 + nt * 16 + lrow;
    float bv = bias1[col];
#pragma unroll
    for (int r = 0; r < 4; r++) {
      int row = m0 + mt * 16 + quad * 4 + r;
      if (row < NN)
        hb[(size_t)row * D2 + col] = f2bf(fmaxf(acc[nt][r] + bv, 0.f));
    }
  }
}

// ---------------------------------------------------------------------------
// out: out = [hb|A2b](K=576) @ Wc2T + bias2
// tile M=32 x N=32, BK=64, 9 K-steps, ONE barrier per step, pinned prefetch.
// ---------------------------------------------------------------------------
__global__ __launch_bounds__(256) void out_mfma(
    const unsigned short* __restrict__ hb, const unsigned short* __restrict__ A2b,
    const unsigned short* __restrict__ Wt, const float* __restrict__ bias2,
    float* __restrict__ out) {
  __shared__ __align__(16) unsigned short Asb[2][32 * 64];   // 8 KB
  __shared__ __align__(16) unsigned short Bsb[2][32 * 64];   // 8 KB
  const int tid = threadIdx.x;
  const int m0 = blockIdx.x * 32;
  const int wv = tid >> 6, lane = tid & 63;
  const int lrow = lane & 15, quad = lane >> 4;
  const int mt = wv >> 1, ntn = wv & 1;   // wave: 16 rows x 16 cols

  const int ar = tid >> 3, ac = tid & 7;
  int gr = m0 + ar; if (gr >= NN) gr = NN - 1;
  const unsigned short* Ah = &hb[(size_t)gr * D2 + ac * 8];     // step 0
  const unsigned short* Aa = &A2b[(size_t)gr * 512 + ac * 8];   // steps 1-8
  const unsigned short* Bp = &Wt[(size_t)ar * 576 + ac * 8];
  const int asw = (ar & 7) << 4;
  const int aw = (ar * 128 + ((ac * 16) ^ asw)) >> 1;

  uint4 ra, rb;

#define O_LOADG(c)                                                       \
  { int kb = (c) * 64;                                                   \
    ra = (kb < 64) ? *(const uint4*)(Ah)                                 \
                   : *(const uint4*)(Aa + (kb - 64));                    \
    rb = *(const uint4*)(Bp + kb); }

#define O_STOREL(buf)                                                    \
  { *(uint4*)&Asb[buf][aw] = ra;                                         \
    *(uint4*)&Bsb[buf][aw] = rb; }

#define O_COMPUTE(buf)                                                   \
  { const int arow = mt * 16 + lrow;                                     \
    const int aswz = (arow & 7) << 4;                                    \
    const int brow = ntn * 16 + lrow;                                    \
    const int bswz = (brow & 7) << 4;                                    \
    _Pragma("unroll")                                                    \
    for (int kk = 0; kk < 2; kk++) {                                     \
      short8 af = *(const short8*)&Asb[buf][(arow * 128 + ((quad * 16 + kk * 64) ^ aswz)) >> 1]; \
      short8 bfr = *(const short8*)&Bsb[buf][(brow * 128 + ((quad * 16 + kk * 64) ^ bswz)) >> 1]; \
      acc = __builtin_amdgcn_mfma_f32_16x16x32_bf16(af, bfr, acc, 0, 0, 0); \
    } }

  float4e acc;
  acc[0]=0.f; acc[1]=0.f; acc[2]=0.f; acc[3]=0.f;

  O_LOADG(0);
  O_STOREL(0);
  __syncthreads();

#pragma unroll
  for (int c = 0; c < 9; c++) {
    if (c < 8) {
      O_LOADG(c + 1);
      __builtin_amdgcn_sched_barrier(0);   // pin prefetch before compute
    }
    O_COMPUTE(c & 1);
    if (c < 8) O_STOREL((c + 1) & 1);
    __syncthreads();
  }

  int col = ntn * 16 + lrow;
  if (col < D3) {
    float bv = bias2[col];
#pragma unroll
    for (int r = 0; r < 4; r++) {
      int row = m0 + mt * 16 + quad * 4 + r;
      if (row < NN)
        out[(size_t)row * D3 + col] = acc[r] + bv;
    }
  }
}

// ---------------------------------------------------------------------------
extern "C" void kernel_launch(void* const* d_in, const int* in_sizes, int n_in,
                              void* d_out, int out_size, void* d_ws,
                              size_t ws_size, hipStream_t stream) {
  const float* x_drug = (const float*)d_in[0];
  const float* drug_w = (const float*)d_in[1];
  const int*   ei     = (const int*)d_in[2];
  const float* basis1 = (const float*)d_in[3];
  const float* comp1  = (const float*)d_in[4];
  const float* root1  = (const float*)d_in[5];
  const float* bias1  = (const float*)d_in[6];
  const float* basis2 = (const float*)d_in[7];
  const float* comp2  = (const float*)d_in[8];
  const float* root2  = (const float*)d_in[9];
  const float* bias2  = (const float*)d_in[10];
  float* out = (float*)d_out;

  float* ws = (float*)d_ws;
  int*   cur  = (int*)ws;                          // 10,016
  int*   rec  = cur + 10016;                       // 1,280,000 (NN*MAXD)
  unsigned short* xb   = (unsigned short*)(rec + NN * MAXD);       // 640,000 f
  unsigned short* hb   = (unsigned short*)((float*)xb + 640000);   // 320,000 f
  unsigned short* Btw  = (unsigned short*)((float*)hb + 320000);   // 131,072 f
  unsigned short* Wc1T = (unsigned short*)((float*)Btw + 131072);  // 36,864 f
  unsigned short* Wc2T = (unsigned short*)((float*)Wc1T + 36864);  // 9,216 f
  float* R1 = (float*)Wc2T + 9216;                 // shared scratch region
  unsigned short* A1b = (unsigned short*)R1;       // 10.24M ushort (20.5MB)
  unsigned short* A2b = (unsigned short*)R1;       // aliases A1b (after hlayer)

  // fused prep: zero cur + all weight transposes (one dispatch)
  prep_kernel<<<CURB + WTBLK + W1BLK + W2BLK, 256, 0, stream>>>(
      drug_w, root1, basis1, root2, basis2, (int4*)cur, Btw, Wc1T, Wc2T);

  // CSR build: scatter rec (single random 4B store/edge); esc now computed
  // in-kernel by the agg kernels (finalize + esc array deleted).
  scatter_kernel<<<(NE + 255) / 256, 256, 0, stream>>>(ei, cur, rec);

  // x = bf16(x_drug @ drug_w) — counted-vmcnt pipelined
  gemm0_mfma<<<NN / 16, 256, 0, stream>>>(x_drug, Btw, xb);

  // layer 1
  agg1e_kernel<<<NN / 4, 256, 0, stream>>>(xb, cur, rec, comp1, A1b);
  hlayer_mfma<<<(NN + 31) / 32, 256, 0, stream>>>(xb, A1b, Wc1T, bias1, hb);

  // layer 2
  agg2e_kernel<<<NN / 4, 256, 0, stream>>>(hb, cur, rec, comp2, A2b);
  out_mfma<<<(NN + 31) / 32, 256, 0, stream>>>(hb, A2b, Wc2T, bias2, out);
}